// Round 4
// baseline (780.704 us; speedup 1.0000x reference)
//
#include <hip/hip_runtime.h>
#include <hip/hip_fp16.h>

#define NA 100000
#define NBATCH 4096
#define NBIN 1971       // 5 maps * 391 atom-ranges + 16 batch-ranges
#define MAPS_BINS 1955  // 5 * 391

typedef _Float16 f16;
typedef f16 half8 __attribute__((ext_vector_type(8)));
typedef f16 half4 __attribute__((ext_vector_type(4)));
typedef float f32x4 __attribute__((ext_vector_type(4)));
union HU { uint4 u; half8 h; f16 s[8]; };

// ---------------- two-level counting sort CSR build ----------------
__device__ __forceinline__ unsigned capbase_of(int b) {
  if (b < 391)  return 0u       + (unsigned)(b       ) * 1536u;
  if (b < 782)  return 600576u  + (unsigned)(b -  391) * 2048u;
  if (b < 1173) return 1401344u + (unsigned)(b -  782) * 2560u;
  if (b < 1564) return 2402304u + (unsigned)(b - 1173) * 1024u;
  if (b < 1955) return 2802688u + (unsigned)(b - 1564) * 1232u;
  return 3284400u + (unsigned)(b - 1955) * 12500u;
}

struct PassAParams {
  const int* row[6];
  int start[6];
  int total;
};

__global__ __launch_bounds__(256) void k_initc(unsigned* ccursor) {
  int b = blockIdx.x * 256 + threadIdx.x;
  if (b < NBIN) ccursor[b] = capbase_of(b);
}

__global__ __launch_bounds__(256) void k_passA(PassAParams pp, unsigned* ccursor,
                                               unsigned* pairs) {
  __shared__ int hist[NBIN];
  __shared__ unsigned hbase[NBIN];
  int t = threadIdx.x;
  for (int b = t; b < NBIN; b += 256) hist[b] = 0;
  __syncthreads();
  int g0 = blockIdx.x * 8192;
  unsigned keys[32];
#pragma unroll
  for (int i = 0; i < 32; i++) {
    int g = g0 + i * 256 + t;
    keys[i] = 0xFFFFFFFFu;
    if (g < pp.total) {
      int m = 0;
#pragma unroll
      for (int j = 1; j < 6; j++) if (g >= pp.start[j]) m = j;
      int e = g - pp.start[m];
      int a = pp.row[m][e];
      int bin = (m < 5) ? m * 391 + (a >> 8) : MAPS_BINS + (a >> 8);
      keys[i] = ((unsigned)bin << 8) | (unsigned)(a & 255);
      atomicAdd(&hist[bin], 1);
    }
  }
  __syncthreads();
  for (int b = t; b < NBIN; b += 256) {
    int h = hist[b];
    hbase[b] = h ? atomicAdd(&ccursor[b], (unsigned)h) : 0u;
  }
  __syncthreads();
#pragma unroll
  for (int i = 0; i < 32; i++) {
    unsigned kv = keys[i];
    if (kv == 0xFFFFFFFFu) continue;
    int bin = (int)(kv >> 8);
    int g = g0 + i * 256 + t;
    int m = 0;
#pragma unroll
    for (int j = 1; j < 6; j++) if (g >= pp.start[j]) m = j;
    int e = g - pp.start[m];
    unsigned pos = atomicAdd(&hbase[bin], 1u);
    pairs[pos] = ((unsigned)e << 8) | (kv & 255u);
  }
}

__global__ __launch_bounds__(256) void k_cscan(const unsigned* ccursor, unsigned* cbase) {
  __shared__ unsigned s[256];
  int t = threadIdx.x;
  unsigned carry = 0;
  for (int c0 = 0; c0 < NBIN; c0 += 256) {
    int b = c0 + t;
    unsigned v = 0;
    if (b < NBIN) v = ccursor[b] - capbase_of(b);
    s[t] = v;
    __syncthreads();
    for (int d = 1; d < 256; d <<= 1) {
      unsigned x = (t >= d) ? s[t - d] : 0;
      __syncthreads();
      s[t] += x;
      __syncthreads();
    }
    if (b < NBIN) cbase[b] = s[t] - v + carry;
    unsigned tot = s[255];
    __syncthreads();
    carry += tot;
  }
}

__global__ __launch_bounds__(256) void k_passB(const unsigned* ccursor, const unsigned* cbase,
                                               const unsigned* pairs, int* bucket,
                                               int* cnt, int* basea) {
  __shared__ int hist[256];
  __shared__ int scn[256];
  __shared__ unsigned cur[256];
  int b = blockIdx.x;
  int t = threadIdx.x;
  unsigned cb0 = capbase_of(b);
  int count = (int)(ccursor[b] - cb0);
  const unsigned* src = pairs + cb0;
  hist[t] = 0;
  __syncthreads();
  for (int i = t; i < count; i += 256) atomicAdd(&hist[src[i] & 255u], 1);
  __syncthreads();
  int h = hist[t];
  scn[t] = h;
  __syncthreads();
  for (int d = 1; d < 256; d <<= 1) {
    int x = (t >= d) ? scn[t - d] : 0;
    __syncthreads();
    scn[t] += x;
    __syncthreads();
  }
  int excl = scn[t] - h;
  unsigned gbase = cbase[b];
  int m, a0, off, amax;
  if (b < MAPS_BINS) { m = b / 391; a0 = (b - m * 391) << 8; off = m * 100000; amax = 100000; }
  else { m = 5; a0 = (b - MAPS_BINS) << 8; off = 500000; amax = NBATCH; }
  if (a0 + t < amax) {
    cnt[off + a0 + t] = h;
    basea[off + a0 + t] = (int)(gbase + (unsigned)excl);
  }
  cur[t] = gbase + (unsigned)excl;
  __syncthreads();
  for (int i = t; i < count; i += 256) {
    unsigned v = src[i];
    unsigned pos = atomicAdd(&cur[v & 255u], 1u);
    bucket[pos] = (int)(v >> 8);
  }
}

// ---------------- feature init (x stored f16) ----------------

__global__ __launch_bounds__(256) void k_atom_init(const int* xa, const float* e0,
                                                   const float* e1, const float* e2, f16* x) {
  int idx = blockIdx.x * 256 + threadIdx.x;
  if (idx >= NA * 16) return;
  int a = idx >> 4, q = idx & 15;
  int f0 = xa[a * 3], f1 = xa[a * 3 + 1], f2 = xa[a * 3 + 2];
  float4 v0 = ((const float4*)e0)[f0 * 16 + q];
  float4 v1 = ((const float4*)e1)[f1 * 16 + q];
  float4 v2 = ((const float4*)e2)[f2 * 16 + q];
  half4 h = {(f16)(v0.x + v1.x + v2.x), (f16)(v0.y + v1.y + v2.y),
             (f16)(v0.z + v1.z + v2.z), (f16)(v0.w + v1.w + v2.w)};
  ((half4*)x)[idx] = h;
}

// ---------------- path/cycle embedding tables -> f16 ----------------

__global__ __launch_bounds__(256) void k_prepT(const float* path_emb, const float* cycle_emb,
                                                f16* T) {
  int t = blockIdx.x * 256 + threadIdx.x;
  if (t >= 1664) return;
  float v = (t < 1152) ? path_emb[t] : cycle_emb[t - 1152];
  T[t] = (f16)v;
}

// ---------------- prepack conv kernels to fp16 MFMA-B layout ----------------

__global__ __launch_bounds__(256) void k_prepB(const float* pK, const float* cK, f16* Bp) {
  int tid = blockIdx.x * 256 + threadIdx.x;
  if (tid >= 10 * 12288) return;
  int set = tid / 12288, pos = tid % 12288;
  int j = pos & 7, lane = (pos >> 3) & 63, kcnt = pos >> 9;
  int kc = kcnt % 6, nt = kcnt / 6;
  int k = kc * 32 + ((lane >> 4) << 3) + j;
  int n = (nt << 4) + (lane & 15);
  int w = k >> 6, ji = k & 63;
  const float* K = (set < 6) ? (pK + set * 3 * 4096) : (cK + (set - 6) * 3 * 4096);
  float v = K[w * 4096 + ji * 64 + n];
  if (set >= 6) v = 0.5f * (v + K[(2 - w) * 4096 + ji * 64 + n]);
  Bp[tid] = (f16)v;
}

// ---------------- prepack 64x64 weights to fp16 MFMA-B layout ----------------

__global__ __launch_bounds__(256) void k_prepW(const float* pW, const float* cW,
                                               const float* pWa, const float* cWa, f16* Wp) {
  int tid = blockIdx.x * 256 + threadIdx.x;
  if (tid >= 20 * 4096) return;
  int set = tid >> 12, pos = tid & 4095;
  int j = pos & 7, lane = (pos >> 3) & 63, ntkc = pos >> 9;
  int kc = ntkc & 1, nt = ntkc >> 1;
  int k = kc * 32 + ((lane >> 4) << 3) + j;
  int n = (nt << 4) + (lane & 15);
  const float* W;
  if (set < 6) W = pW + set * 4096;
  else if (set < 10) W = cW + (set - 6) * 4096;
  else if (set < 16) W = pWa + (set - 10) * 4096;
  else W = cWa + (set - 16) * 4096;
  Wp[tid] = (f16)W[k * 64 + n];
}

// ---------------- fused a2p+conv (swapped-operand MFMA, 2 barriers) ----------------
// mfma(Wfrag, Xfrag, acc): D = (X@W)^T -> lane&15 = row, (lane>>4)*4+reg = 4 consecutive
// channels. acc is bias-initialized (bias add for free). Epilogue 1 is owner-lane 8B RMW
// in LDS; epilogue 2 reads own-lane LDS rows and stores final value DIRECTLY to global
// (no barrier, no copy-out loop; L2 merges the 8B stores within each 128B row).

struct FusedParams {
  const f16* xh;
  const int* gidx[3];
  const int* vals[3];
  const f16* tab[3];
  __half* xp[3];
  const f16* Wa[3];
  const float* ba[3];
  const f16* Bp[3];
  const float* Kb[3];
  int k[3];
  int P[3];
  int ppb[3];
  int blk_start[3];
  int nseg;
  int cyclic;
  int use_tab;
};

__global__ __launch_bounds__(256) void k_fused(FusedParams p) {
  __shared__ uint4 xn4[873];     // 97 rows x 9 uint4 (72 f16/row, row 96 = zero pad)
  __shared__ __align__(16) float bl[64];
  __shared__ __align__(16) float kbl[64];
  __shared__ int ridx[96];
  int bid = blockIdx.x;
  int seg = 0;
#pragma unroll
  for (int i = 1; i < 3; i++) if (i < p.nseg && bid >= p.blk_start[i]) seg = i;
  int kk = p.k[seg], ppb = p.ppb[seg], P = p.P[seg];
  int cyc = p.cyclic;
  int t = threadIdx.x;
  int p0 = (bid - p.blk_start[seg]) * ppb;
  int np = min(ppb, P - p0);
  int R = np * kk;    // always a multiple of 16 for these ppb choices
  int mtb = R >> 4;
  long ebase = (long)p0 * kk;
  if (t < 64) { bl[t] = p.ba[seg][t]; kbl[t] = p.Kb[seg][t]; }
  if (t < 9) { uint4 z; z.x = z.y = z.z = z.w = 0; xn4[96 * 9 + t] = z; }
  if (t < R) ridx[t] = p.gidx[seg][ebase + t];
  uint4* xg = (uint4*)(p.xp[seg] + (long)ebase * 64);
  if (p.use_tab) {
    const uint4* tabu = (const uint4*)p.tab[seg];
    const int* vseg = p.vals[seg];
    for (int idx = t; idx < R * 8; idx += 256) {
      int row = idx >> 3, ch = idx & 7;
      xn4[row * 9 + ch] = tabu[vseg[ebase + row] * 8 + ch];
    }
  } else {
    for (int idx = t; idx < R * 8; idx += 256)
      xn4[(idx >> 3) * 9 + (idx & 7)] = xg[idx];
  }
  __syncthreads();
  int lane = t & 63, wid = t >> 6;
  int wave_n = wid & 1, wave_m = wid >> 1;
  int mtA = (mtb + 1) >> 1;
  int m0 = wave_m ? mtA : 0;
  int mcnt = wave_m ? (mtb - mtA) : mtA;
  f16* xnh = (f16*)xn4;
  int chq0 = wave_n * 32 + ((lane >> 4) << 2);       // jn=0 channel quad
  int chq1 = chq0 + 16;                               // jn=1 channel quad
  // stage A: xn += relu(x_gather @ Wa + ba)   (bias via acc init)
  {
    f32x4 b0 = {bl[chq0], bl[chq0 + 1], bl[chq0 + 2], bl[chq0 + 3]};
    f32x4 b1 = {bl[chq1], bl[chq1 + 1], bl[chq1 + 2], bl[chq1 + 3]};
    f32x4 acc1[3][2];
#pragma unroll
    for (int i = 0; i < 3; i++) { acc1[i][0] = b0; acc1[i][1] = b1; }
    const uint4* Wau = (const uint4*)p.Wa[seg];
    HU w[2][2];
#pragma unroll
    for (int kc = 0; kc < 2; kc++)
#pragma unroll
      for (int jn = 0; jn < 2; jn++)
        w[kc][jn].u = Wau[(((wave_n * 2 + jn) << 1) + kc) * 64 + lane];
    const uint4* xh4 = (const uint4*)p.xh;
    int rowid[3];
#pragma unroll
    for (int i = 0; i < 3; i++)
      if (i < mcnt) rowid[i] = ridx[((m0 + i) << 4) + (lane & 15)];
    HU xa[3], xb[3];
#pragma unroll
    for (int i = 0; i < 3; i++)
      if (i < mcnt) {
        xa[i].u = xh4[(long)rowid[i] * 8 + (lane >> 4)];
        xb[i].u = xh4[(long)rowid[i] * 8 + 4 + (lane >> 4)];
      }
#pragma unroll
    for (int i = 0; i < 3; i++) {
      if (i >= mcnt) continue;
#pragma unroll
      for (int jn = 0; jn < 2; jn++) {
        acc1[i][jn] = __builtin_amdgcn_mfma_f32_16x16x32_f16(w[0][jn].h, xa[i].h, acc1[i][jn], 0, 0, 0);
        acc1[i][jn] = __builtin_amdgcn_mfma_f32_16x16x32_f16(w[1][jn].h, xb[i].h, acc1[i][jn], 0, 0, 0);
      }
    }
#pragma unroll
    for (int i = 0; i < 3; i++) {
      if (i >= mcnt) continue;
      int r = ((m0 + i) << 4) + (lane & 15);
#pragma unroll
      for (int jn = 0; jn < 2; jn++) {
        int chq = jn ? chq1 : chq0;
        f16* pxl = xnh + r * 72 + chq;
        half4 old = *(half4*)pxl;
        half4 nv;
#pragma unroll
        for (int reg = 0; reg < 4; reg++) {
          float v = acc1[i][jn][reg];
          v = v > 0.f ? v : 0.f;
          nv[reg] = (f16)((float)old[reg] + v);
        }
        *(half4*)pxl = nv;
      }
    }
  }
  __syncthreads();
  // conv MFMAs reading xn4 (incl. neighbor rows); bias via acc init
  f32x4 k0 = {kbl[chq0], kbl[chq0 + 1], kbl[chq0 + 2], kbl[chq0 + 3]};
  f32x4 k1 = {kbl[chq1], kbl[chq1 + 1], kbl[chq1 + 2], kbl[chq1 + 3]};
  f32x4 acc2[3][2];
#pragma unroll
  for (int i = 0; i < 3; i++) { acc2[i][0] = k0; acc2[i][1] = k1; }
  int rdw[3][3];
#pragma unroll
  for (int i = 0; i < 3; i++) {
    if (i >= mcnt) continue;
    int mr = ((m0 + i) << 4) + (lane & 15);
    int sm = mr % kk;
    rdw[i][1] = mr;
    rdw[i][0] = (sm >= 1) ? mr - 1 : (cyc ? mr + kk - 1 : 96);
    rdw[i][2] = (sm + 1 < kk) ? mr + 1 : (cyc ? mr + 1 - kk : 96);
  }
  const uint4* Bg = (const uint4*)p.Bp[seg];
  for (int kc = 0; kc < 6; kc++) {
    int w_ = kc >> 1;
    int chunk = ((kc & 1) << 2) + (lane >> 4);
    HU ak[2], xv[3];
#pragma unroll
    for (int jn = 0; jn < 2; jn++)
      ak[jn].u = Bg[((wave_n * 2 + jn) * 6 + kc) * 64 + lane];
#pragma unroll
    for (int i = 0; i < 3; i++)
      if (i < mcnt) xv[i].u = xn4[rdw[i][w_] * 9 + chunk];
#pragma unroll
    for (int i = 0; i < 3; i++)
      if (i < mcnt) {
#pragma unroll
        for (int jn = 0; jn < 2; jn++)
          acc2[i][jn] = __builtin_amdgcn_mfma_f32_16x16x32_f16(ak[jn].h, xv[i].h, acc2[i][jn], 0, 0, 0);
      }
  }
  // epilogue 2: final = xn + relu(conv), owner-lane read from LDS, store direct to global
  f16* xph = (f16*)p.xp[seg];
#pragma unroll
  for (int i = 0; i < 3; i++) {
    if (i >= mcnt) continue;
    int r = ((m0 + i) << 4) + (lane & 15);
#pragma unroll
    for (int jn = 0; jn < 2; jn++) {
      int chq = jn ? chq1 : chq0;
      half4 old = *(half4*)(xnh + r * 72 + chq);
      half4 nv;
#pragma unroll
      for (int reg = 0; reg < 4; reg++) {
        float v = acc2[i][jn][reg];
        v = v > 0.f ? v : 0.f;
        nv[reg] = (f16)((float)old[reg] + v);
      }
      *(half4*)(xph + ((ebase + r) << 6) + chq) = nv;
    }
  }
}

// ---------------- p2a apply v2: CSR gather (no atomics, no acc buffers) ----------------

struct Apply2Params {
  const f16* xp[3];
  const int* cnt[3];
  const int* basea[3];
  const int* bucket;
  const f16* Wp[3];
  const float* bias[3];
  int nm;
};

__global__ __launch_bounds__(256) void k_apply2(Apply2Params p, f16* x) {
  __shared__ uint4 Af[512];
  __shared__ float bl[64];
  int t = threadIdx.x;
  int a0 = blockIdx.x * 64;
  int lane = t & 63, wid = t >> 6;
  int al = t >> 2, q = t & 3;
  int atom = a0 + al;
  f32x4 addv[4];
#pragma unroll
  for (int nt = 0; nt < 4; nt++) { f32x4 z = {0.f, 0.f, 0.f, 0.f}; addv[nt] = z; }
  for (int mi = 0; mi < p.nm; mi++) {
    __syncthreads();
    if (t < 64) bl[t] = p.bias[mi][t];
    float s[16];
#pragma unroll
    for (int i = 0; i < 16; i++) s[i] = 0.f;
    int cb = 0, base = 0;
    if (atom < NA) { cb = p.cnt[mi][atom]; base = p.basea[mi][atom]; }
    const uint4* xpu = (const uint4*)p.xp[mi];
    for (int i = 0; i < cb; i++) {
      int e = p.bucket[base + i];
      HU v0, v1;
      v0.u = xpu[(long)e * 8 + q * 2];
      v1.u = xpu[(long)e * 8 + q * 2 + 1];
#pragma unroll
      for (int j = 0; j < 8; j++) { s[j] += (float)v0.s[j]; s[8 + j] += (float)v1.s[j]; }
    }
    float inv = 1.f / (float)(cb > 0 ? cb : 1);
    HU o0, o1;
#pragma unroll
    for (int j = 0; j < 8; j++) { o0.s[j] = (f16)(s[j] * inv); o1.s[j] = (f16)(s[8 + j] * inv); }
    int jb = ((al >> 4) * 2 + (q >> 1)) * 64 + (q & 1) * 32 + (al & 15);
    Af[jb] = o0.u;
    Af[jb + 16] = o1.u;
    __syncthreads();
    HU af0, af1;
    af0.u = Af[((wid << 1) + 0) * 64 + lane];
    af1.u = Af[((wid << 1) + 1) * 64 + lane];
    const uint4* Wu = (const uint4*)p.Wp[mi];
#pragma unroll
    for (int nt = 0; nt < 4; nt++) {
      HU b0, b1;
      b0.u = Wu[((nt << 1) + 0) * 64 + lane];
      b1.u = Wu[((nt << 1) + 1) * 64 + lane];
      float bv = bl[nt * 16 + (lane & 15)];
      f32x4 z = {bv, bv, bv, bv};
      z = __builtin_amdgcn_mfma_f32_16x16x32_f16(af0.h, b0.h, z, 0, 0, 0);
      z = __builtin_amdgcn_mfma_f32_16x16x32_f16(af1.h, b1.h, z, 0, 0, 0);
#pragma unroll
      for (int r = 0; r < 4; r++) {
        float vv = z[r];
        addv[nt][r] += vv > 0.f ? vv : 0.f;
      }
    }
  }
  int rowb = a0 + wid * 16 + ((lane >> 4) << 2);
#pragma unroll
  for (int nt = 0; nt < 4; nt++) {
    int n = nt * 16 + (lane & 15);
#pragma unroll
    for (int r = 0; r < 4; r++) {
      int atomw = rowb + r;
      if (atomw < NA) {
        long oi = (long)atomw * 64 + n;
        x[oi] = (f16)((float)x[oi] + addv[nt][r]);
      }
    }
  }
}

// ---------------- batch mean over f16 x ----------------

__global__ __launch_bounds__(256) void k_meanscatter(const f16* src, const int* bucket,
                                                     const int* basea, const int* cnta,
                                                     float* dst, int nseg) {
  int wid = (blockIdx.x * 256 + threadIdx.x) >> 6;
  int lane = threadIdx.x & 63;
  if (wid >= nseg) return;
  int b0 = basea[wid], cnt = cnta[wid];
  float s = 0.f;
  for (int i = 0; i < cnt; i++) {
    int e = bucket[b0 + i];
    s += (float)src[(long)e * 64 + lane];
  }
  dst[(long)wid * 64 + lane] = s / (float)(cnt > 0 ? cnt : 1);
}

// ---------------- head gemm ----------------

__global__ __launch_bounds__(256) void k_head(const float* g1, const float* W,
                                              const float* bias, float* g2) {
  __shared__ float Wl[4096];
  __shared__ float inl[32 * 64];
  __shared__ float bl[64];
  int t = threadIdx.x;
  int brow = blockIdx.x * 32;
#pragma unroll
  for (int i = 0; i < 4; i++) ((float4*)Wl)[t + 256 * i] = ((const float4*)W)[t + 256 * i];
  if (t < 64) bl[t] = bias[t];
  __syncthreads();
#pragma unroll
  for (int i = 0; i < 2; i++) {
    int idx = t + 256 * i;
    int r = idx >> 4, q = idx & 15;
    ((float4*)inl)[idx] = ((const float4*)(g1 + (long)(brow + r) * 64))[q];
  }
  __syncthreads();
  int c = t & 63, rq = t >> 6;
  float acc[8];
#pragma unroll
  for (int i = 0; i < 8; i++) acc[i] = 0.f;
  for (int j = 0; j < 64; j += 4) {
    float w0 = Wl[(j + 0) * 64 + c], w1 = Wl[(j + 1) * 64 + c];
    float w2 = Wl[(j + 2) * 64 + c], w3 = Wl[(j + 3) * 64 + c];
#pragma unroll
    for (int i = 0; i < 8; i++) {
      int r = rq * 8 + i;
      float4 v = *(const float4*)&inl[r * 64 + j];
      acc[i] += v.x * w0 + v.y * w1 + v.z * w2 + v.w * w3;
    }
  }
#pragma unroll
  for (int i = 0; i < 8; i++) {
    long r = brow + rq * 8 + i;
    float v = acc[i] + bl[c];
    g2[r * 64 + c] = v > 0.f ? v : 0.f;
  }
}

__global__ __launch_bounds__(256) void k_final(const float* g2, const float* linW,
                                               const float* linb, float* out) {
  int wid = (blockIdx.x * 256 + threadIdx.x) >> 6;
  int lane = threadIdx.x & 63;
  if (wid >= NBATCH) return;
  float v = g2[(long)wid * 64 + lane] * linW[lane];
  for (int o = 32; o > 0; o >>= 1) v += __shfl_down(v, o, 64);
  if (lane == 0) out[wid] = v + linb[0];
}

__global__ __launch_bounds__(256) void k_zero_out(float* out, int n) {
  for (int i = blockIdx.x * 256 + threadIdx.x; i < n; i += gridDim.x * 256) out[i] = 0.f;
}

// ---------------- launcher ----------------

extern "C" void kernel_launch(void* const* d_in, const int* in_sizes, int n_in,
                              void* d_out, int out_size, void* d_ws, size_t ws_size,
                              hipStream_t stream) {
  (void)in_sizes; (void)n_in;

  const int* x_atom = (const int*)d_in[0];
  const int* vals[5] = {(const int*)d_in[1], (const int*)d_in[4], (const int*)d_in[7],
                        (const int*)d_in[10], (const int*)d_in[13]};
  const int* rowm[5] = {(const int*)d_in[2], (const int*)d_in[5], (const int*)d_in[8],
                        (const int*)d_in[11], (const int*)d_in[14]};
  const int* batch = (const int*)d_in[16];
  const float* aemb0 = (const float*)d_in[17];
  const float* aemb1 = (const float*)d_in[18];
  const float* aemb2 = (const float*)d_in[19];
  const float* path_emb = (const float*)d_in[20];
  const float* cycle_emb = (const float*)d_in[21];
  const float* pW_a2p = (const float*)d_in[22];
  const float* pb_a2p = (const float*)d_in[23];
  const float* pW_p2a = (const float*)d_in[24];
  const float* pb_p2a = (const float*)d_in[25];
  const float* pK = (const float*)d_in[26];
  const float* pKb = (const float*)d_in[27];
  const float* cW_a2p = (const float*)d_in[28];
  const float* cb_a2p = (const float*)d_in[29];
  const float* cW_p2a = (const float*)d_in[30];
  const float* cb_p2a = (const float*)d_in[31];
  const float* cK = (const float*)d_in[32];
  const float* cKb = (const float*)d_in[33];
  const float* alW = (const float*)d_in[34];
  const float* alb = (const float*)d_in[35];
  const float* linW = (const float*)d_in[36];
  const float* linb = (const float*)d_in[37];

  static const int Em[5] = {300000, 400000, 500000, 200000, 240000};
  static const int Km[5] = {3, 4, 5, 5, 6};
  static const int Ppb[5] = {32, 24, 16, 16, 16};
  const int CNT_N = 5 * 100000 + NBATCH;  // 504096
  const int BUCKET_N = 1640000 + NA;      // 1740000

  char* ws = (char*)d_ws;
  size_t off = 0;
  auto alloc = [&](size_t nbytes) -> char* {
    char* p = ws + off;
    off = (off + nbytes + 255) & ~(size_t)255;
    return p;
  };
  f16* x = (f16*)alloc((size_t)NA * 64 * 2);   // f16 master
  __half* xp[5];
  for (int m = 0; m < 5; m++) xp[m] = (__half*)alloc((size_t)Em[m] * 64 * 2);
  float* g1 = (float*)alloc((size_t)NBATCH * 64 * 4);
  float* g2 = (float*)alloc((size_t)NBATCH * 64 * 4);
  int* cnt = (int*)alloc((size_t)CNT_N * 4);
  int* basea = (int*)alloc((size_t)CNT_N * 4);
  int* bucket = (int*)alloc((size_t)BUCKET_N * 4);
  unsigned* ccursor = (unsigned*)alloc((size_t)NBIN * 4);
  unsigned* cbase = (unsigned*)alloc((size_t)NBIN * 4);
  f16* Bp = (f16*)alloc((size_t)10 * 12288 * 2);
  f16* Wpk = (f16*)alloc((size_t)20 * 4096 * 2);
  f16* Tabs = (f16*)alloc((size_t)1664 * 2);
  // pairs array (~14 MB) aliases xp[2]: consumed by k_passB before k_fused writes xp[2].
  unsigned* pairs = (unsigned*)xp[2];

  if (ws_size < off) {
    k_zero_out<<<16, 256, 0, stream>>>((float*)d_out, out_size);
    return;
  }

  // ---- CSR build: two-level counting sort
  PassAParams pp;
  {
    int s = 0;
    for (int m = 0; m < 5; m++) { pp.row[m] = rowm[m]; pp.start[m] = s; s += Em[m]; }
    pp.row[5] = batch; pp.start[5] = s;
    pp.total = s + NA;  // 1740000
  }
  k_initc<<<8, 256, 0, stream>>>(ccursor);
  k_passA<<<(1740000 + 8191) / 8192, 256, 0, stream>>>(pp, ccursor, pairs);
  k_cscan<<<1, 256, 0, stream>>>(ccursor, cbase);
  k_passB<<<NBIN, 256, 0, stream>>>(ccursor, cbase, pairs, bucket, cnt, basea);

  // ---- prepack weights + tables + feature init
  k_prepB<<<480, 256, 0, stream>>>(pK, cK, Bp);
  k_prepW<<<320, 256, 0, stream>>>(pW_p2a, cW_p2a, pW_a2p, cW_a2p, Wpk);
  k_prepT<<<7, 256, 0, stream>>>(path_emb, cycle_emb, Tabs);
  k_atom_init<<<NA * 16 / 256, 256, 0, stream>>>(x_atom, aemb0, aemb1, aemb2, x);

  int apply_blocks = (NA + 63) / 64;  // 1563

  auto p2aW = [&](int l, int m) -> const f16* {
    return (m < 3) ? Wpk + (size_t)(l * 3 + m) * 4096
                   : Wpk + (size_t)(6 + l * 2 + (m - 3)) * 4096;
  };
  auto p2aB = [&](int l, int m) -> const float* {
    return (m < 3) ? pb_p2a + (l * 3 + m) * 64 : cb_p2a + (l * 2 + (m - 3)) * 64;
  };

  for (int l = 0; l < 2; l++) {
    // === paths group (maps 0..2), non-cyclic
    {
      FusedParams fp{};
      fp.nseg = 3; fp.cyclic = 0; fp.xh = x; fp.use_tab = (l == 0) ? 1 : 0;
      int bs = 0;
      for (int m = 0; m < 3; m++) {
        fp.gidx[m] = rowm[m]; fp.xp[m] = xp[m];
        fp.vals[m] = vals[m]; fp.tab[m] = Tabs + (size_t)m * 384;
        fp.Wa[m] = Wpk + (size_t)(10 + l * 3 + m) * 4096;
        fp.ba[m] = pb_a2p + (l * 3 + m) * 64;
        fp.Bp[m] = Bp + (size_t)(l * 3 + m) * 12288;
        fp.Kb[m] = pKb + (l * 3 + m) * 64;
        fp.k[m] = Km[m]; fp.P[m] = Em[m] / Km[m]; fp.ppb[m] = Ppb[m];
        fp.blk_start[m] = bs;
        bs += (fp.P[m] + fp.ppb[m] - 1) / fp.ppb[m];
      }
      k_fused<<<bs, 256, 0, stream>>>(fp);

      Apply2Params ap{};
      ap.nm = 3; ap.bucket = bucket;
      for (int m = 0; m < 3; m++) {
        ap.xp[m] = (const f16*)xp[m];
        ap.cnt[m] = cnt + (size_t)m * 100000;
        ap.basea[m] = basea + (size_t)m * 100000;
        ap.Wp[m] = p2aW(l, m); ap.bias[m] = p2aB(l, m);
      }
      k_apply2<<<apply_blocks, 256, 0, stream>>>(ap, x);
    }
    // === cycles group (maps 3..4), cyclic
    {
      FusedParams fp{};
      fp.nseg = 2; fp.cyclic = 1; fp.xh = x; fp.use_tab = (l == 0) ? 1 : 0;
      int bs = 0;
      for (int m = 3; m < 5; m++) {
        int i = m - 3;
        fp.gidx[i] = rowm[m]; fp.xp[i] = xp[m];
        fp.vals[i] = vals[m]; fp.tab[i] = Tabs + 1152 + (size_t)i * 256;
        fp.Wa[i] = Wpk + (size_t)(16 + l * 2 + i) * 4096;
        fp.ba[i] = cb_a2p + (l * 2 + i) * 64;
        fp.Bp[i] = Bp + (size_t)(6 + l * 2 + i) * 12288;
        fp.Kb[i] = cKb + (l * 2 + i) * 64;
        fp.k[i] = Km[m]; fp.P[i] = Em[m] / Km[m]; fp.ppb[i] = Ppb[m];
        fp.blk_start[i] = bs;
        bs += (fp.P[i] + fp.ppb[i] - 1) / fp.ppb[i];
      }
      k_fused<<<bs, 256, 0, stream>>>(fp);

      Apply2Params ap{};
      ap.nm = 2; ap.bucket = bucket;
      for (int m = 3; m < 5; m++) {
        int i = m - 3;
        ap.xp[i] = (const f16*)xp[m];
        ap.cnt[i] = cnt + (size_t)m * 100000;
        ap.basea[i] = basea + (size_t)m * 100000;
        ap.Wp[i] = p2aW(l, m); ap.bias[i] = p2aB(l, m);
      }
      k_apply2<<<apply_blocks, 256, 0, stream>>>(ap, x);
    }
  }

  // ---- head (basea entries for the batch segment are GLOBAL bucket positions)
  k_meanscatter<<<NBATCH / 4, 256, 0, stream>>>(x, bucket, basea + 500000,
                                                cnt + 500000, g1, NBATCH);
  k_head<<<NBATCH / 32, 256, 0, stream>>>(g1, alW, alb, g2);
  k_final<<<NBATCH / 4, 256, 0, stream>>>(g2, linW, linb, (float*)d_out);
}

// Round 5
// 740.171 us; speedup vs baseline: 1.0548x; 1.0548x over previous
//
#include <hip/hip_runtime.h>
#include <hip/hip_fp16.h>

#define NA 100000
#define NBATCH 4096
#define NBIN 1971       // 5 maps * 391 atom-ranges + 16 batch-ranges
#define MAPS_BINS 1955  // 5 * 391

typedef _Float16 f16;
typedef f16 half8 __attribute__((ext_vector_type(8)));
typedef f16 half4 __attribute__((ext_vector_type(4)));
typedef float f32x4 __attribute__((ext_vector_type(4)));
union HU { uint4 u; half8 h; f16 s[8]; };

// ---------------- two-level counting sort CSR build ----------------
__device__ __forceinline__ unsigned capbase_of(int b) {
  if (b < 391)  return 0u       + (unsigned)(b       ) * 1536u;
  if (b < 782)  return 600576u  + (unsigned)(b -  391) * 2048u;
  if (b < 1173) return 1401344u + (unsigned)(b -  782) * 2560u;
  if (b < 1564) return 2402304u + (unsigned)(b - 1173) * 1024u;
  if (b < 1955) return 2802688u + (unsigned)(b - 1564) * 1232u;
  return 3284400u + (unsigned)(b - 1955) * 12500u;
}

struct PassAParams {
  const int* row[6];
  int start[6];
  int total;
};

__global__ __launch_bounds__(256) void k_initc(unsigned* ccursor) {
  int b = blockIdx.x * 256 + threadIdx.x;
  if (b < NBIN) ccursor[b] = capbase_of(b);
}

__global__ __launch_bounds__(256) void k_passA(PassAParams pp, unsigned* ccursor,
                                               unsigned* pairs) {
  __shared__ int hist[NBIN];
  __shared__ unsigned hbase[NBIN];
  int t = threadIdx.x;
  for (int b = t; b < NBIN; b += 256) hist[b] = 0;
  __syncthreads();
  int g0 = blockIdx.x * 8192;
  unsigned keys[32];
#pragma unroll
  for (int i = 0; i < 32; i++) {
    int g = g0 + i * 256 + t;
    keys[i] = 0xFFFFFFFFu;
    if (g < pp.total) {
      int m = 0;
#pragma unroll
      for (int j = 1; j < 6; j++) if (g >= pp.start[j]) m = j;
      int e = g - pp.start[m];
      int a = pp.row[m][e];
      int bin = (m < 5) ? m * 391 + (a >> 8) : MAPS_BINS + (a >> 8);
      keys[i] = ((unsigned)bin << 8) | (unsigned)(a & 255);
      atomicAdd(&hist[bin], 1);
    }
  }
  __syncthreads();
  for (int b = t; b < NBIN; b += 256) {
    int h = hist[b];
    hbase[b] = h ? atomicAdd(&ccursor[b], (unsigned)h) : 0u;
  }
  __syncthreads();
#pragma unroll
  for (int i = 0; i < 32; i++) {
    unsigned kv = keys[i];
    if (kv == 0xFFFFFFFFu) continue;
    int bin = (int)(kv >> 8);
    int g = g0 + i * 256 + t;
    int m = 0;
#pragma unroll
    for (int j = 1; j < 6; j++) if (g >= pp.start[j]) m = j;
    int e = g - pp.start[m];
    unsigned pos = atomicAdd(&hbase[bin], 1u);
    pairs[pos] = ((unsigned)e << 8) | (kv & 255u);
  }
}

__global__ __launch_bounds__(256) void k_cscan(const unsigned* ccursor, unsigned* cbase) {
  __shared__ unsigned s[256];
  int t = threadIdx.x;
  unsigned carry = 0;
  for (int c0 = 0; c0 < NBIN; c0 += 256) {
    int b = c0 + t;
    unsigned v = 0;
    if (b < NBIN) v = ccursor[b] - capbase_of(b);
    s[t] = v;
    __syncthreads();
    for (int d = 1; d < 256; d <<= 1) {
      unsigned x = (t >= d) ? s[t - d] : 0;
      __syncthreads();
      s[t] += x;
      __syncthreads();
    }
    if (b < NBIN) cbase[b] = s[t] - v + carry;
    unsigned tot = s[255];
    __syncthreads();
    carry += tot;
  }
}

__global__ __launch_bounds__(256) void k_passB(const unsigned* ccursor, const unsigned* cbase,
                                               const unsigned* pairs, int* bucket,
                                               int* cnt, int* basea) {
  __shared__ int hist[256];
  __shared__ int scn[256];
  __shared__ unsigned cur[256];
  int b = blockIdx.x;
  int t = threadIdx.x;
  unsigned cb0 = capbase_of(b);
  int count = (int)(ccursor[b] - cb0);
  const unsigned* src = pairs + cb0;
  hist[t] = 0;
  __syncthreads();
  for (int i = t; i < count; i += 256) atomicAdd(&hist[src[i] & 255u], 1);
  __syncthreads();
  int h = hist[t];
  scn[t] = h;
  __syncthreads();
  for (int d = 1; d < 256; d <<= 1) {
    int x = (t >= d) ? scn[t - d] : 0;
    __syncthreads();
    scn[t] += x;
    __syncthreads();
  }
  int excl = scn[t] - h;
  unsigned gbase = cbase[b];
  int m, a0, off, amax;
  if (b < MAPS_BINS) { m = b / 391; a0 = (b - m * 391) << 8; off = m * 100000; amax = 100000; }
  else { m = 5; a0 = (b - MAPS_BINS) << 8; off = 500000; amax = NBATCH; }
  if (a0 + t < amax) {
    cnt[off + a0 + t] = h;
    basea[off + a0 + t] = (int)(gbase + (unsigned)excl);
  }
  cur[t] = gbase + (unsigned)excl;
  __syncthreads();
  for (int i = t; i < count; i += 256) {
    unsigned v = src[i];
    unsigned pos = atomicAdd(&cur[v & 255u], 1u);
    bucket[pos] = (int)(v >> 8);
  }
}

// ---------------- feature init (x stored f16) ----------------

__global__ __launch_bounds__(256) void k_atom_init(const int* xa, const float* e0,
                                                   const float* e1, const float* e2, f16* x) {
  int idx = blockIdx.x * 256 + threadIdx.x;
  if (idx >= NA * 16) return;
  int a = idx >> 4, q = idx & 15;
  int f0 = xa[a * 3], f1 = xa[a * 3 + 1], f2 = xa[a * 3 + 2];
  float4 v0 = ((const float4*)e0)[f0 * 16 + q];
  float4 v1 = ((const float4*)e1)[f1 * 16 + q];
  float4 v2 = ((const float4*)e2)[f2 * 16 + q];
  half4 h = {(f16)(v0.x + v1.x + v2.x), (f16)(v0.y + v1.y + v2.y),
             (f16)(v0.z + v1.z + v2.z), (f16)(v0.w + v1.w + v2.w)};
  ((half4*)x)[idx] = h;
}

// ---------------- path/cycle embedding tables -> f16 ----------------

__global__ __launch_bounds__(256) void k_prepT(const float* path_emb, const float* cycle_emb,
                                                f16* T) {
  int t = blockIdx.x * 256 + threadIdx.x;
  if (t >= 1664) return;
  float v = (t < 1152) ? path_emb[t] : cycle_emb[t - 1152];
  T[t] = (f16)v;
}

// ---------------- prepack conv kernels to fp16 MFMA-B layout ----------------

__global__ __launch_bounds__(256) void k_prepB(const float* pK, const float* cK, f16* Bp) {
  int tid = blockIdx.x * 256 + threadIdx.x;
  if (tid >= 10 * 12288) return;
  int set = tid / 12288, pos = tid % 12288;
  int j = pos & 7, lane = (pos >> 3) & 63, kcnt = pos >> 9;
  int kc = kcnt % 6, nt = kcnt / 6;
  int k = kc * 32 + ((lane >> 4) << 3) + j;
  int n = (nt << 4) + (lane & 15);
  int w = k >> 6, ji = k & 63;
  const float* K = (set < 6) ? (pK + set * 3 * 4096) : (cK + (set - 6) * 3 * 4096);
  float v = K[w * 4096 + ji * 64 + n];
  if (set >= 6) v = 0.5f * (v + K[(2 - w) * 4096 + ji * 64 + n]);
  Bp[tid] = (f16)v;
}

// ---------------- prepack 64x64 weights to fp16 MFMA-B layout ----------------

__global__ __launch_bounds__(256) void k_prepW(const float* pW, const float* cW,
                                               const float* pWa, const float* cWa, f16* Wp) {
  int tid = blockIdx.x * 256 + threadIdx.x;
  if (tid >= 20 * 4096) return;
  int set = tid >> 12, pos = tid & 4095;
  int j = pos & 7, lane = (pos >> 3) & 63, ntkc = pos >> 9;
  int kc = ntkc & 1, nt = ntkc >> 1;
  int k = kc * 32 + ((lane >> 4) << 3) + j;
  int n = (nt << 4) + (lane & 15);
  const float* W;
  if (set < 6) W = pW + set * 4096;
  else if (set < 10) W = cW + (set - 6) * 4096;
  else if (set < 16) W = pWa + (set - 10) * 4096;
  else W = cWa + (set - 16) * 4096;
  Wp[tid] = (f16)W[k * 64 + n];
}

// ---------------- fused a2p+conv (swapped-operand MFMA) ----------------
// mfma(Wfrag, Xfrag, acc): D = (X@W)^T -> lane&15 = row, (lane>>4)*4+reg = 4 consecutive
// channels. acc is bias-initialized (bias add for free). Both epilogues are owner-lane
// 8B RMW on the xn LDS tile; final copy-out is coalesced uint4 (direct scattered global
// stores measured SLOWER: R4 132us vs this structure 112us).

struct FusedParams {
  const f16* xh;
  const int* gidx[3];
  const int* vals[3];
  const f16* tab[3];
  __half* xp[3];
  const f16* Wa[3];
  const float* ba[3];
  const f16* Bp[3];
  const float* Kb[3];
  int k[3];
  int P[3];
  int ppb[3];
  int blk_start[3];
  int nseg;
  int cyclic;
  int use_tab;
};

__global__ __launch_bounds__(256) void k_fused(FusedParams p) {
  __shared__ uint4 xn4[873];     // 97 rows x 9 uint4 (72 f16/row, row 96 = zero pad)
  __shared__ __align__(16) float bl[64];
  __shared__ __align__(16) float kbl[64];
  __shared__ int ridx[96];
  int bid = blockIdx.x;
  int seg = 0;
#pragma unroll
  for (int i = 1; i < 3; i++) if (i < p.nseg && bid >= p.blk_start[i]) seg = i;
  int kk = p.k[seg], ppb = p.ppb[seg], P = p.P[seg];
  int cyc = p.cyclic;
  int t = threadIdx.x;
  int p0 = (bid - p.blk_start[seg]) * ppb;
  int np = min(ppb, P - p0);
  int R = np * kk;    // always a multiple of 16 for these ppb choices
  int mtb = R >> 4;
  long ebase = (long)p0 * kk;
  if (t < 64) { bl[t] = p.ba[seg][t]; kbl[t] = p.Kb[seg][t]; }
  if (t < 9) { uint4 z; z.x = z.y = z.z = z.w = 0; xn4[96 * 9 + t] = z; }
  if (t < R) ridx[t] = p.gidx[seg][ebase + t];
  uint4* xg = (uint4*)(p.xp[seg] + (long)ebase * 64);
  if (p.use_tab) {
    const uint4* tabu = (const uint4*)p.tab[seg];
    const int* vseg = p.vals[seg];
    for (int idx = t; idx < R * 8; idx += 256) {
      int row = idx >> 3, ch = idx & 7;
      xn4[row * 9 + ch] = tabu[vseg[ebase + row] * 8 + ch];
    }
  } else {
    for (int idx = t; idx < R * 8; idx += 256)
      xn4[(idx >> 3) * 9 + (idx & 7)] = xg[idx];
  }
  __syncthreads();
  int lane = t & 63, wid = t >> 6;
  int wave_n = wid & 1, wave_m = wid >> 1;
  int mtA = (mtb + 1) >> 1;
  int m0 = wave_m ? mtA : 0;
  int mcnt = wave_m ? (mtb - mtA) : mtA;
  f16* xnh = (f16*)xn4;
  int chq0 = wave_n * 32 + ((lane >> 4) << 2);       // jn=0 channel quad
  int chq1 = chq0 + 16;                               // jn=1 channel quad
  // stage A: xn += relu(x_gather @ Wa + ba)   (bias via acc init)
  {
    f32x4 b0 = {bl[chq0], bl[chq0 + 1], bl[chq0 + 2], bl[chq0 + 3]};
    f32x4 b1 = {bl[chq1], bl[chq1 + 1], bl[chq1 + 2], bl[chq1 + 3]};
    f32x4 acc1[3][2];
#pragma unroll
    for (int i = 0; i < 3; i++) { acc1[i][0] = b0; acc1[i][1] = b1; }
    const uint4* Wau = (const uint4*)p.Wa[seg];
    HU w[2][2];
#pragma unroll
    for (int kc = 0; kc < 2; kc++)
#pragma unroll
      for (int jn = 0; jn < 2; jn++)
        w[kc][jn].u = Wau[(((wave_n * 2 + jn) << 1) + kc) * 64 + lane];
    const uint4* xh4 = (const uint4*)p.xh;
    int rowid[3];
#pragma unroll
    for (int i = 0; i < 3; i++)
      if (i < mcnt) rowid[i] = ridx[((m0 + i) << 4) + (lane & 15)];
    HU xa[3], xb[3];
#pragma unroll
    for (int i = 0; i < 3; i++)
      if (i < mcnt) {
        xa[i].u = xh4[(long)rowid[i] * 8 + (lane >> 4)];
        xb[i].u = xh4[(long)rowid[i] * 8 + 4 + (lane >> 4)];
      }
#pragma unroll
    for (int i = 0; i < 3; i++) {
      if (i >= mcnt) continue;
#pragma unroll
      for (int jn = 0; jn < 2; jn++) {
        acc1[i][jn] = __builtin_amdgcn_mfma_f32_16x16x32_f16(w[0][jn].h, xa[i].h, acc1[i][jn], 0, 0, 0);
        acc1[i][jn] = __builtin_amdgcn_mfma_f32_16x16x32_f16(w[1][jn].h, xb[i].h, acc1[i][jn], 0, 0, 0);
      }
    }
#pragma unroll
    for (int i = 0; i < 3; i++) {
      if (i >= mcnt) continue;
      int r = ((m0 + i) << 4) + (lane & 15);
#pragma unroll
      for (int jn = 0; jn < 2; jn++) {
        int chq = jn ? chq1 : chq0;
        f16* pxl = xnh + r * 72 + chq;
        half4 old = *(half4*)pxl;
        half4 nv;
#pragma unroll
        for (int reg = 0; reg < 4; reg++) {
          float v = acc1[i][jn][reg];
          v = v > 0.f ? v : 0.f;
          nv[reg] = (f16)((float)old[reg] + v);
        }
        *(half4*)pxl = nv;
      }
    }
  }
  __syncthreads();
  // conv MFMAs reading xn4 (incl. neighbor rows); bias via acc init
  f32x4 k0 = {kbl[chq0], kbl[chq0 + 1], kbl[chq0 + 2], kbl[chq0 + 3]};
  f32x4 k1 = {kbl[chq1], kbl[chq1 + 1], kbl[chq1 + 2], kbl[chq1 + 3]};
  f32x4 acc2[3][2];
#pragma unroll
  for (int i = 0; i < 3; i++) { acc2[i][0] = k0; acc2[i][1] = k1; }
  int rdw[3][3];
#pragma unroll
  for (int i = 0; i < 3; i++) {
    if (i >= mcnt) continue;
    int mr = ((m0 + i) << 4) + (lane & 15);
    int sm = mr % kk;
    rdw[i][1] = mr;
    rdw[i][0] = (sm >= 1) ? mr - 1 : (cyc ? mr + kk - 1 : 96);
    rdw[i][2] = (sm + 1 < kk) ? mr + 1 : (cyc ? mr + 1 - kk : 96);
  }
  const uint4* Bg = (const uint4*)p.Bp[seg];
  for (int kc = 0; kc < 6; kc++) {
    int w_ = kc >> 1;
    int chunk = ((kc & 1) << 2) + (lane >> 4);
    HU ak[2], xv[3];
#pragma unroll
    for (int jn = 0; jn < 2; jn++)
      ak[jn].u = Bg[((wave_n * 2 + jn) * 6 + kc) * 64 + lane];
#pragma unroll
    for (int i = 0; i < 3; i++)
      if (i < mcnt) xv[i].u = xn4[rdw[i][w_] * 9 + chunk];
#pragma unroll
    for (int i = 0; i < 3; i++)
      if (i < mcnt) {
#pragma unroll
        for (int jn = 0; jn < 2; jn++)
          acc2[i][jn] = __builtin_amdgcn_mfma_f32_16x16x32_f16(ak[jn].h, xv[i].h, acc2[i][jn], 0, 0, 0);
      }
  }
  __syncthreads();  // conv reads of xn4 complete before overwrite
  // epilogue 2: final = xn + relu(conv), owner-lane RMW in LDS
#pragma unroll
  for (int i = 0; i < 3; i++) {
    if (i >= mcnt) continue;
    int r = ((m0 + i) << 4) + (lane & 15);
#pragma unroll
    for (int jn = 0; jn < 2; jn++) {
      int chq = jn ? chq1 : chq0;
      f16* pxl = xnh + r * 72 + chq;
      half4 old = *(half4*)pxl;
      half4 nv;
#pragma unroll
      for (int reg = 0; reg < 4; reg++) {
        float v = acc2[i][jn][reg];
        v = v > 0.f ? v : 0.f;
        nv[reg] = (f16)((float)old[reg] + v);
      }
      *(half4*)pxl = nv;
    }
  }
  __syncthreads();
  // coalesced copy-out
  for (int idx = t; idx < R * 8; idx += 256)
    xg[idx] = xn4[(idx >> 3) * 9 + (idx & 7)];
}

// ---------------- p2a apply v2: CSR gather (no atomics, no acc buffers) ----------------

struct Apply2Params {
  const f16* xp[3];
  const int* cnt[3];
  const int* basea[3];
  const int* bucket;
  const f16* Wp[3];
  const float* bias[3];
  int nm;
};

__global__ __launch_bounds__(256) void k_apply2(Apply2Params p, f16* x) {
  __shared__ uint4 Af[512];
  __shared__ float bl[64];
  int t = threadIdx.x;
  int a0 = blockIdx.x * 64;
  int lane = t & 63, wid = t >> 6;
  int al = t >> 2, q = t & 3;
  int atom = a0 + al;
  f32x4 addv[4];
#pragma unroll
  for (int nt = 0; nt < 4; nt++) { f32x4 z = {0.f, 0.f, 0.f, 0.f}; addv[nt] = z; }
  for (int mi = 0; mi < p.nm; mi++) {
    __syncthreads();
    if (t < 64) bl[t] = p.bias[mi][t];
    float s[16];
#pragma unroll
    for (int i = 0; i < 16; i++) s[i] = 0.f;
    int cb = 0, base = 0;
    if (atom < NA) { cb = p.cnt[mi][atom]; base = p.basea[mi][atom]; }
    const uint4* xpu = (const uint4*)p.xp[mi];
    for (int i = 0; i < cb; i++) {
      int e = p.bucket[base + i];
      HU v0, v1;
      v0.u = xpu[(long)e * 8 + q * 2];
      v1.u = xpu[(long)e * 8 + q * 2 + 1];
#pragma unroll
      for (int j = 0; j < 8; j++) { s[j] += (float)v0.s[j]; s[8 + j] += (float)v1.s[j]; }
    }
    float inv = 1.f / (float)(cb > 0 ? cb : 1);
    HU o0, o1;
#pragma unroll
    for (int j = 0; j < 8; j++) { o0.s[j] = (f16)(s[j] * inv); o1.s[j] = (f16)(s[8 + j] * inv); }
    int jb = ((al >> 4) * 2 + (q >> 1)) * 64 + (q & 1) * 32 + (al & 15);
    Af[jb] = o0.u;
    Af[jb + 16] = o1.u;
    __syncthreads();
    HU af0, af1;
    af0.u = Af[((wid << 1) + 0) * 64 + lane];
    af1.u = Af[((wid << 1) + 1) * 64 + lane];
    const uint4* Wu = (const uint4*)p.Wp[mi];
#pragma unroll
    for (int nt = 0; nt < 4; nt++) {
      HU b0, b1;
      b0.u = Wu[((nt << 1) + 0) * 64 + lane];
      b1.u = Wu[((nt << 1) + 1) * 64 + lane];
      float bv = bl[nt * 16 + (lane & 15)];
      f32x4 z = {bv, bv, bv, bv};
      z = __builtin_amdgcn_mfma_f32_16x16x32_f16(af0.h, b0.h, z, 0, 0, 0);
      z = __builtin_amdgcn_mfma_f32_16x16x32_f16(af1.h, b1.h, z, 0, 0, 0);
#pragma unroll
      for (int r = 0; r < 4; r++) {
        float vv = z[r];
        addv[nt][r] += vv > 0.f ? vv : 0.f;
      }
    }
  }
  int rowb = a0 + wid * 16 + ((lane >> 4) << 2);
#pragma unroll
  for (int nt = 0; nt < 4; nt++) {
    int n = nt * 16 + (lane & 15);
#pragma unroll
    for (int r = 0; r < 4; r++) {
      int atomw = rowb + r;
      if (atomw < NA) {
        long oi = (long)atomw * 64 + n;
        x[oi] = (f16)((float)x[oi] + addv[nt][r]);
      }
    }
  }
}

// ---------------- batch mean over f16 x ----------------

__global__ __launch_bounds__(256) void k_meanscatter(const f16* src, const int* bucket,
                                                     const int* basea, const int* cnta,
                                                     float* dst, int nseg) {
  int wid = (blockIdx.x * 256 + threadIdx.x) >> 6;
  int lane = threadIdx.x & 63;
  if (wid >= nseg) return;
  int b0 = basea[wid], cnt = cnta[wid];
  float s = 0.f;
  for (int i = 0; i < cnt; i++) {
    int e = bucket[b0 + i];
    s += (float)src[(long)e * 64 + lane];
  }
  dst[(long)wid * 64 + lane] = s / (float)(cnt > 0 ? cnt : 1);
}

// ---------------- head gemm ----------------

__global__ __launch_bounds__(256) void k_head(const float* g1, const float* W,
                                              const float* bias, float* g2) {
  __shared__ float Wl[4096];
  __shared__ float inl[32 * 64];
  __shared__ float bl[64];
  int t = threadIdx.x;
  int brow = blockIdx.x * 32;
#pragma unroll
  for (int i = 0; i < 4; i++) ((float4*)Wl)[t + 256 * i] = ((const float4*)W)[t + 256 * i];
  if (t < 64) bl[t] = bias[t];
  __syncthreads();
#pragma unroll
  for (int i = 0; i < 2; i++) {
    int idx = t + 256 * i;
    int r = idx >> 4, q = idx & 15;
    ((float4*)inl)[idx] = ((const float4*)(g1 + (long)(brow + r) * 64))[q];
  }
  __syncthreads();
  int c = t & 63, rq = t >> 6;
  float acc[8];
#pragma unroll
  for (int i = 0; i < 8; i++) acc[i] = 0.f;
  for (int j = 0; j < 64; j += 4) {
    float w0 = Wl[(j + 0) * 64 + c], w1 = Wl[(j + 1) * 64 + c];
    float w2 = Wl[(j + 2) * 64 + c], w3 = Wl[(j + 3) * 64 + c];
#pragma unroll
    for (int i = 0; i < 8; i++) {
      int r = rq * 8 + i;
      float4 v = *(const float4*)&inl[r * 64 + j];
      acc[i] += v.x * w0 + v.y * w1 + v.z * w2 + v.w * w3;
    }
  }
#pragma unroll
  for (int i = 0; i < 8; i++) {
    long r = brow + rq * 8 + i;
    float v = acc[i] + bl[c];
    g2[r * 64 + c] = v > 0.f ? v : 0.f;
  }
}

__global__ __launch_bounds__(256) void k_final(const float* g2, const float* linW,
                                               const float* linb, float* out) {
  int wid = (blockIdx.x * 256 + threadIdx.x) >> 6;
  int lane = threadIdx.x & 63;
  if (wid >= NBATCH) return;
  float v = g2[(long)wid * 64 + lane] * linW[lane];
  for (int o = 32; o > 0; o >>= 1) v += __shfl_down(v, o, 64);
  if (lane == 0) out[wid] = v + linb[0];
}

__global__ __launch_bounds__(256) void k_zero_out(float* out, int n) {
  for (int i = blockIdx.x * 256 + threadIdx.x; i < n; i += gridDim.x * 256) out[i] = 0.f;
}

// ---------------- launcher ----------------

extern "C" void kernel_launch(void* const* d_in, const int* in_sizes, int n_in,
                              void* d_out, int out_size, void* d_ws, size_t ws_size,
                              hipStream_t stream) {
  (void)in_sizes; (void)n_in;

  const int* x_atom = (const int*)d_in[0];
  const int* vals[5] = {(const int*)d_in[1], (const int*)d_in[4], (const int*)d_in[7],
                        (const int*)d_in[10], (const int*)d_in[13]};
  const int* rowm[5] = {(const int*)d_in[2], (const int*)d_in[5], (const int*)d_in[8],
                        (const int*)d_in[11], (const int*)d_in[14]};
  const int* batch = (const int*)d_in[16];
  const float* aemb0 = (const float*)d_in[17];
  const float* aemb1 = (const float*)d_in[18];
  const float* aemb2 = (const float*)d_in[19];
  const float* path_emb = (const float*)d_in[20];
  const float* cycle_emb = (const float*)d_in[21];
  const float* pW_a2p = (const float*)d_in[22];
  const float* pb_a2p = (const float*)d_in[23];
  const float* pW_p2a = (const float*)d_in[24];
  const float* pb_p2a = (const float*)d_in[25];
  const float* pK = (const float*)d_in[26];
  const float* pKb = (const float*)d_in[27];
  const float* cW_a2p = (const float*)d_in[28];
  const float* cb_a2p = (const float*)d_in[29];
  const float* cW_p2a = (const float*)d_in[30];
  const float* cb_p2a = (const float*)d_in[31];
  const float* cK = (const float*)d_in[32];
  const float* cKb = (const float*)d_in[33];
  const float* alW = (const float*)d_in[34];
  const float* alb = (const float*)d_in[35];
  const float* linW = (const float*)d_in[36];
  const float* linb = (const float*)d_in[37];

  static const int Em[5] = {300000, 400000, 500000, 200000, 240000};
  static const int Km[5] = {3, 4, 5, 5, 6};
  static const int Ppb[5] = {32, 24, 16, 16, 16};
  const int CNT_N = 5 * 100000 + NBATCH;  // 504096
  const int BUCKET_N = 1640000 + NA;      // 1740000

  char* ws = (char*)d_ws;
  size_t off = 0;
  auto alloc = [&](size_t nbytes) -> char* {
    char* p = ws + off;
    off = (off + nbytes + 255) & ~(size_t)255;
    return p;
  };
  f16* x = (f16*)alloc((size_t)NA * 64 * 2);   // f16 master
  __half* xp[5];
  for (int m = 0; m < 5; m++) xp[m] = (__half*)alloc((size_t)Em[m] * 64 * 2);
  float* g1 = (float*)alloc((size_t)NBATCH * 64 * 4);
  float* g2 = (float*)alloc((size_t)NBATCH * 64 * 4);
  int* cnt = (int*)alloc((size_t)CNT_N * 4);
  int* basea = (int*)alloc((size_t)CNT_N * 4);
  int* bucket = (int*)alloc((size_t)BUCKET_N * 4);
  unsigned* ccursor = (unsigned*)alloc((size_t)NBIN * 4);
  unsigned* cbase = (unsigned*)alloc((size_t)NBIN * 4);
  f16* Bp = (f16*)alloc((size_t)10 * 12288 * 2);
  f16* Wpk = (f16*)alloc((size_t)20 * 4096 * 2);
  f16* Tabs = (f16*)alloc((size_t)1664 * 2);
  // pairs array (~14 MB) aliases xp[2]: consumed by k_passB before k_fused writes xp[2].
  unsigned* pairs = (unsigned*)xp[2];

  if (ws_size < off) {
    k_zero_out<<<16, 256, 0, stream>>>((float*)d_out, out_size);
    return;
  }

  // ---- CSR build: two-level counting sort
  PassAParams pp;
  {
    int s = 0;
    for (int m = 0; m < 5; m++) { pp.row[m] = rowm[m]; pp.start[m] = s; s += Em[m]; }
    pp.row[5] = batch; pp.start[5] = s;
    pp.total = s + NA;  // 1740000
  }
  k_initc<<<8, 256, 0, stream>>>(ccursor);
  k_passA<<<(1740000 + 8191) / 8192, 256, 0, stream>>>(pp, ccursor, pairs);
  k_cscan<<<1, 256, 0, stream>>>(ccursor, cbase);
  k_passB<<<NBIN, 256, 0, stream>>>(ccursor, cbase, pairs, bucket, cnt, basea);

  // ---- prepack weights + tables + feature init
  k_prepB<<<480, 256, 0, stream>>>(pK, cK, Bp);
  k_prepW<<<320, 256, 0, stream>>>(pW_p2a, cW_p2a, pW_a2p, cW_a2p, Wpk);
  k_prepT<<<7, 256, 0, stream>>>(path_emb, cycle_emb, Tabs);
  k_atom_init<<<NA * 16 / 256, 256, 0, stream>>>(x_atom, aemb0, aemb1, aemb2, x);

  int apply_blocks = (NA + 63) / 64;  // 1563

  auto p2aW = [&](int l, int m) -> const f16* {
    return (m < 3) ? Wpk + (size_t)(l * 3 + m) * 4096
                   : Wpk + (size_t)(6 + l * 2 + (m - 3)) * 4096;
  };
  auto p2aB = [&](int l, int m) -> const float* {
    return (m < 3) ? pb_p2a + (l * 3 + m) * 64 : cb_p2a + (l * 2 + (m - 3)) * 64;
  };

  for (int l = 0; l < 2; l++) {
    // === paths group (maps 0..2), non-cyclic
    {
      FusedParams fp{};
      fp.nseg = 3; fp.cyclic = 0; fp.xh = x; fp.use_tab = (l == 0) ? 1 : 0;
      int bs = 0;
      for (int m = 0; m < 3; m++) {
        fp.gidx[m] = rowm[m]; fp.xp[m] = xp[m];
        fp.vals[m] = vals[m]; fp.tab[m] = Tabs + (size_t)m * 384;
        fp.Wa[m] = Wpk + (size_t)(10 + l * 3 + m) * 4096;
        fp.ba[m] = pb_a2p + (l * 3 + m) * 64;
        fp.Bp[m] = Bp + (size_t)(l * 3 + m) * 12288;
        fp.Kb[m] = pKb + (l * 3 + m) * 64;
        fp.k[m] = Km[m]; fp.P[m] = Em[m] / Km[m]; fp.ppb[m] = Ppb[m];
        fp.blk_start[m] = bs;
        bs += (fp.P[m] + fp.ppb[m] - 1) / fp.ppb[m];
      }
      k_fused<<<bs, 256, 0, stream>>>(fp);

      Apply2Params ap{};
      ap.nm = 3; ap.bucket = bucket;
      for (int m = 0; m < 3; m++) {
        ap.xp[m] = (const f16*)xp[m];
        ap.cnt[m] = cnt + (size_t)m * 100000;
        ap.basea[m] = basea + (size_t)m * 100000;
        ap.Wp[m] = p2aW(l, m); ap.bias[m] = p2aB(l, m);
      }
      k_apply2<<<apply_blocks, 256, 0, stream>>>(ap, x);
    }
    // === cycles group (maps 3..4), cyclic
    {
      FusedParams fp{};
      fp.nseg = 2; fp.cyclic = 1; fp.xh = x; fp.use_tab = (l == 0) ? 1 : 0;
      int bs = 0;
      for (int m = 3; m < 5; m++) {
        int i = m - 3;
        fp.gidx[i] = rowm[m]; fp.xp[i] = xp[m];
        fp.vals[i] = vals[m]; fp.tab[i] = Tabs + 1152 + (size_t)i * 256;
        fp.Wa[i] = Wpk + (size_t)(16 + l * 2 + i) * 4096;
        fp.ba[i] = cb_a2p + (l * 2 + i) * 64;
        fp.Bp[i] = Bp + (size_t)(6 + l * 2 + i) * 12288;
        fp.Kb[i] = cKb + (l * 2 + i) * 64;
        fp.k[i] = Km[m]; fp.P[i] = Em[m] / Km[m]; fp.ppb[i] = Ppb[m];
        fp.blk_start[i] = bs;
        bs += (fp.P[i] + fp.ppb[i] - 1) / fp.ppb[i];
      }
      k_fused<<<bs, 256, 0, stream>>>(fp);

      Apply2Params ap{};
      ap.nm = 2; ap.bucket = bucket;
      for (int m = 3; m < 5; m++) {
        int i = m - 3;
        ap.xp[i] = (const f16*)xp[m];
        ap.cnt[i] = cnt + (size_t)m * 100000;
        ap.basea[i] = basea + (size_t)m * 100000;
        ap.Wp[i] = p2aW(l, m); ap.bias[i] = p2aB(l, m);
      }
      k_apply2<<<apply_blocks, 256, 0, stream>>>(ap, x);
    }
  }

  // ---- head (basea entries for the batch segment are GLOBAL bucket positions)
  k_meanscatter<<<NBATCH / 4, 256, 0, stream>>>(x, bucket, basea + 500000,
                                                cnt + 500000, g1, NBATCH);
  k_head<<<NBATCH / 32, 256, 0, stream>>>(g1, alW, alb, g2);
  k_final<<<NBATCH / 4, 256, 0, stream>>>(g2, linW, linb, (float*)d_out);
}

// Round 6
// 716.729 us; speedup vs baseline: 1.0893x; 1.0327x over previous
//
#include <hip/hip_runtime.h>
#include <hip/hip_fp16.h>

#define NA 100000
#define NBATCH 4096
#define NBIN 1971       // 5 maps * 391 atom-ranges + 16 batch-ranges
#define MAPS_BINS 1955  // 5 * 391

typedef _Float16 f16;
typedef f16 half8 __attribute__((ext_vector_type(8)));
typedef f16 half4 __attribute__((ext_vector_type(4)));
typedef float f32x4 __attribute__((ext_vector_type(4)));
union HU { uint4 u; half8 h; f16 s[8]; };

// ---------------- two-level counting sort CSR build ----------------
__device__ __forceinline__ unsigned capbase_of(int b) {
  if (b < 391)  return 0u       + (unsigned)(b       ) * 1536u;
  if (b < 782)  return 600576u  + (unsigned)(b -  391) * 2048u;
  if (b < 1173) return 1401344u + (unsigned)(b -  782) * 2560u;
  if (b < 1564) return 2402304u + (unsigned)(b - 1173) * 1024u;
  if (b < 1955) return 2802688u + (unsigned)(b - 1564) * 1232u;
  return 3284400u + (unsigned)(b - 1955) * 12500u;
}

struct PassAParams {
  const int* row[6];
  int start[6];
  int total;
};

__global__ __launch_bounds__(256) void k_passA(PassAParams pp, unsigned* ccursor,
                                               unsigned* pairs) {
  __shared__ int hist[NBIN];
  __shared__ unsigned hbase[NBIN];
  int t = threadIdx.x;
  for (int b = t; b < NBIN; b += 256) hist[b] = 0;
  __syncthreads();
  int g0 = blockIdx.x * 8192;
  unsigned keys[32];
#pragma unroll
  for (int i = 0; i < 32; i++) {
    int g = g0 + i * 256 + t;
    keys[i] = 0xFFFFFFFFu;
    if (g < pp.total) {
      int m = 0;
#pragma unroll
      for (int j = 1; j < 6; j++) if (g >= pp.start[j]) m = j;
      int e = g - pp.start[m];
      int a = pp.row[m][e];
      int bin = (m < 5) ? m * 391 + (a >> 8) : MAPS_BINS + (a >> 8);
      keys[i] = ((unsigned)bin << 8) | (unsigned)(a & 255);
      atomicAdd(&hist[bin], 1);
    }
  }
  __syncthreads();
  for (int b = t; b < NBIN; b += 256) {
    int h = hist[b];
    hbase[b] = h ? atomicAdd(&ccursor[b], (unsigned)h) : 0u;
  }
  __syncthreads();
#pragma unroll
  for (int i = 0; i < 32; i++) {
    unsigned kv = keys[i];
    if (kv == 0xFFFFFFFFu) continue;
    int bin = (int)(kv >> 8);
    int g = g0 + i * 256 + t;
    int m = 0;
#pragma unroll
    for (int j = 1; j < 6; j++) if (g >= pp.start[j]) m = j;
    int e = g - pp.start[m];
    unsigned pos = atomicAdd(&hbase[bin], 1u);
    pairs[pos] = ((unsigned)e << 8) | (kv & 255u);
  }
}

__global__ __launch_bounds__(256) void k_cscan(const unsigned* ccursor, unsigned* cbase) {
  __shared__ unsigned s[256];
  int t = threadIdx.x;
  unsigned carry = 0;
  for (int c0 = 0; c0 < NBIN; c0 += 256) {
    int b = c0 + t;
    unsigned v = 0;
    if (b < NBIN) v = ccursor[b] - capbase_of(b);
    s[t] = v;
    __syncthreads();
    for (int d = 1; d < 256; d <<= 1) {
      unsigned x = (t >= d) ? s[t - d] : 0;
      __syncthreads();
      s[t] += x;
      __syncthreads();
    }
    if (b < NBIN) cbase[b] = s[t] - v + carry;
    unsigned tot = s[255];
    __syncthreads();
    carry += tot;
  }
}

__global__ __launch_bounds__(256) void k_passB(const unsigned* ccursor, const unsigned* cbase,
                                               const unsigned* pairs, int* bucket,
                                               int* cnt, int* basea) {
  __shared__ int hist[256];
  __shared__ int scn[256];
  __shared__ unsigned cur[256];
  int b = blockIdx.x;
  int t = threadIdx.x;
  unsigned cb0 = capbase_of(b);
  int count = (int)(ccursor[b] - cb0);
  const unsigned* src = pairs + cb0;
  hist[t] = 0;
  __syncthreads();
  for (int i = t; i < count; i += 256) atomicAdd(&hist[src[i] & 255u], 1);
  __syncthreads();
  int h = hist[t];
  scn[t] = h;
  __syncthreads();
  for (int d = 1; d < 256; d <<= 1) {
    int x = (t >= d) ? scn[t - d] : 0;
    __syncthreads();
    scn[t] += x;
    __syncthreads();
  }
  int excl = scn[t] - h;
  unsigned gbase = cbase[b];
  int m, a0, off, amax;
  if (b < MAPS_BINS) { m = b / 391; a0 = (b - m * 391) << 8; off = m * 100000; amax = 100000; }
  else { m = 5; a0 = (b - MAPS_BINS) << 8; off = 500000; amax = NBATCH; }
  if (a0 + t < amax) {
    cnt[off + a0 + t] = h;
    basea[off + a0 + t] = (int)(gbase + (unsigned)excl);
  }
  cur[t] = gbase + (unsigned)excl;
  __syncthreads();
  for (int i = t; i < count; i += 256) {
    unsigned v = src[i];
    unsigned pos = atomicAdd(&cur[v & 255u], 1u);
    bucket[pos] = (int)(v >> 8);
  }
}

// ---------------- merged prep kernel: atom_init + prepB + prepW + prepT + initc --------

struct PrepParams {
  const int* xa; const float *e0; const float *e1; const float *e2; f16* x;
  const float *pK; const float *cK; f16* Bp;
  const float *pW; const float *cW; const float *pWa; const float *cWa; f16* Wp;
  const float *path_emb; const float *cycle_emb; f16* T;
  unsigned* ccursor;
};

__global__ __launch_bounds__(256) void k_prep(PrepParams q) {
  int bid = blockIdx.x, t = threadIdx.x;
  if (bid < 6250) {
    // atom feature init: x[a][0:64] = e0[f0]+e1[f1]+e2[f2], f16 (idx < NA*16 exactly)
    int idx = bid * 256 + t;
    int a = idx >> 4, qq = idx & 15;
    int f0 = q.xa[a * 3], f1 = q.xa[a * 3 + 1], f2 = q.xa[a * 3 + 2];
    float4 v0 = ((const float4*)q.e0)[f0 * 16 + qq];
    float4 v1 = ((const float4*)q.e1)[f1 * 16 + qq];
    float4 v2 = ((const float4*)q.e2)[f2 * 16 + qq];
    half4 h = {(f16)(v0.x + v1.x + v2.x), (f16)(v0.y + v1.y + v2.y),
               (f16)(v0.z + v1.z + v2.z), (f16)(v0.w + v1.w + v2.w)};
    ((half4*)q.x)[idx] = h;
  } else if (bid < 6730) {
    // conv kernels -> MFMA-B fp16 layout (tid < 122880 exactly)
    int tid = (bid - 6250) * 256 + t;
    int set = tid / 12288, pos = tid % 12288;
    int j = pos & 7, lane = (pos >> 3) & 63, kcnt = pos >> 9;
    int kc = kcnt % 6, nt = kcnt / 6;
    int k = kc * 32 + ((lane >> 4) << 3) + j;
    int n = (nt << 4) + (lane & 15);
    int w = k >> 6, ji = k & 63;
    const float* K = (set < 6) ? (q.pK + set * 3 * 4096) : (q.cK + (set - 6) * 3 * 4096);
    float v = K[w * 4096 + ji * 64 + n];
    if (set >= 6) v = 0.5f * (v + K[(2 - w) * 4096 + ji * 64 + n]);
    q.Bp[tid] = (f16)v;
  } else if (bid < 7050) {
    // 64x64 weights -> MFMA-B fp16 layout (tid < 81920 exactly)
    int tid = (bid - 6730) * 256 + t;
    int set = tid >> 12, pos = tid & 4095;
    int j = pos & 7, lane = (pos >> 3) & 63, ntkc = pos >> 9;
    int kc = ntkc & 1, nt = ntkc >> 1;
    int k = kc * 32 + ((lane >> 4) << 3) + j;
    int n = (nt << 4) + (lane & 15);
    const float* W;
    if (set < 6) W = q.pW + set * 4096;
    else if (set < 10) W = q.cW + (set - 6) * 4096;
    else if (set < 16) W = q.pWa + (set - 10) * 4096;
    else W = q.cWa + (set - 16) * 4096;
    q.Wp[tid] = (f16)W[k * 64 + n];
  } else {
    int idx = (bid - 7050) * 256 + t;
    if (idx < 1664) {
      float v = (idx < 1152) ? q.path_emb[idx] : q.cycle_emb[idx - 1152];
      q.T[idx] = (f16)v;
    }
    if (idx < NBIN) q.ccursor[idx] = capbase_of(idx);
  }
}

// ---------------- fused a2p+conv (swapped-operand MFMA) ----------------
// mfma(Wfrag, Xfrag, acc): D = (X@W)^T -> lane&15 = row, (lane>>4)*4+reg = 4 consecutive
// channels. Epilogues are owner-lane 8B RMW on the xn LDS tile; coalesced uint4 copy-out.
// R3-measured-best structure (112us): zero-init acc + bias in epilogue + interleaved
// gathers. (R4 direct-global-store: 132us; R5 bias-init+batched-gather: 119us.)
// New: prevs/nexts LDS tables replace 3 runtime %kk divisions per thread.

struct FusedParams {
  const f16* xh;
  const int* gidx[3];
  const int* vals[3];
  const f16* tab[3];
  __half* xp[3];
  const f16* Wa[3];
  const float* ba[3];
  const f16* Bp[3];
  const float* Kb[3];
  int k[3];
  int P[3];
  int ppb[3];
  int blk_start[3];
  int nseg;
  int cyclic;
  int use_tab;
};

__global__ __launch_bounds__(256) void k_fused(FusedParams p) {
  __shared__ uint4 xn4[873];     // 97 rows x 9 uint4 (72 f16/row, row 96 = zero pad)
  __shared__ float bl[64], kbl[64];
  __shared__ int ridx[96];
  __shared__ short prevs[96], nexts[96];
  int bid = blockIdx.x;
  int seg = 0;
#pragma unroll
  for (int i = 1; i < 3; i++) if (i < p.nseg && bid >= p.blk_start[i]) seg = i;
  int kk = p.k[seg], ppb = p.ppb[seg], P = p.P[seg];
  int cyc = p.cyclic;
  int t = threadIdx.x;
  int p0 = (bid - p.blk_start[seg]) * ppb;
  int np = min(ppb, P - p0);
  int R = np * kk;    // always a multiple of 16 for these ppb choices
  int mtb = R >> 4;
  long ebase = (long)p0 * kk;
  if (t < 64) { bl[t] = p.ba[seg][t]; kbl[t] = p.Kb[seg][t]; }
  if (t < 9) { uint4 z; z.x = z.y = z.z = z.w = 0; xn4[96 * 9 + t] = z; }
  if (t < R) ridx[t] = p.gidx[seg][ebase + t];
  if (t < 96) {
    int sm = t % kk;  // one div per 96 threads (vs 3 per 256 threads before)
    prevs[t] = (short)((sm >= 1) ? t - 1 : (cyc ? t + kk - 1 : 96));
    nexts[t] = (short)((sm + 1 < kk) ? t + 1 : (cyc ? t + 1 - kk : 96));
  }
  uint4* xg = (uint4*)(p.xp[seg] + (long)ebase * 64);
  if (p.use_tab) {
    const uint4* tabu = (const uint4*)p.tab[seg];
    const int* vseg = p.vals[seg];
    for (int idx = t; idx < R * 8; idx += 256) {
      int row = idx >> 3, ch = idx & 7;
      xn4[row * 9 + ch] = tabu[vseg[ebase + row] * 8 + ch];
    }
  } else {
    for (int idx = t; idx < R * 8; idx += 256)
      xn4[(idx >> 3) * 9 + (idx & 7)] = xg[idx];
  }
  __syncthreads();
  int lane = t & 63, wid = t >> 6;
  int wave_n = wid & 1, wave_m = wid >> 1;
  int mtA = (mtb + 1) >> 1;
  int m0 = wave_m ? mtA : 0;
  int mcnt = wave_m ? (mtb - mtA) : mtA;
  f16* xnh = (f16*)xn4;
  // stage A: xn += relu(x_gather @ Wa + ba)
  {
    f32x4 acc1[3][2];
#pragma unroll
    for (int i = 0; i < 3; i++)
#pragma unroll
      for (int jn = 0; jn < 2; jn++) { f32x4 z = {0.f, 0.f, 0.f, 0.f}; acc1[i][jn] = z; }
    const uint4* Wau = (const uint4*)p.Wa[seg];
    HU w[2][2];
#pragma unroll
    for (int kc = 0; kc < 2; kc++)
#pragma unroll
      for (int jn = 0; jn < 2; jn++)
        w[kc][jn].u = Wau[(((wave_n * 2 + jn) << 1) + kc) * 64 + lane];
    const uint4* xh4 = (const uint4*)p.xh;
#pragma unroll
    for (int i = 0; i < 3; i++) {
      if (i >= mcnt) continue;
      int rowid = ridx[((m0 + i) << 4) + (lane & 15)];
      HU xa, xb;
      xa.u = xh4[(long)rowid * 8 + (lane >> 4)];
      xb.u = xh4[(long)rowid * 8 + 4 + (lane >> 4)];
#pragma unroll
      for (int jn = 0; jn < 2; jn++) {
        acc1[i][jn] = __builtin_amdgcn_mfma_f32_16x16x32_f16(w[0][jn].h, xa.h, acc1[i][jn], 0, 0, 0);
        acc1[i][jn] = __builtin_amdgcn_mfma_f32_16x16x32_f16(w[1][jn].h, xb.h, acc1[i][jn], 0, 0, 0);
      }
    }
#pragma unroll
    for (int i = 0; i < 3; i++) {
      if (i >= mcnt) continue;
      int r = ((m0 + i) << 4) + (lane & 15);
#pragma unroll
      for (int jn = 0; jn < 2; jn++) {
        int chq = wave_n * 32 + jn * 16 + ((lane >> 4) << 2);
        f16* pxl = xnh + r * 72 + chq;
        half4 old = *(half4*)pxl;
        half4 nv;
#pragma unroll
        for (int reg = 0; reg < 4; reg++) {
          float v = acc1[i][jn][reg] + bl[chq + reg];
          v = v > 0.f ? v : 0.f;
          nv[reg] = (f16)((float)old[reg] + v);
        }
        *(half4*)pxl = nv;
      }
    }
  }
  __syncthreads();
  // conv MFMAs reading xn4 (incl. neighbor rows via LDS tables)
  f32x4 acc2[3][2];
#pragma unroll
  for (int i = 0; i < 3; i++)
#pragma unroll
    for (int jn = 0; jn < 2; jn++) { f32x4 z = {0.f, 0.f, 0.f, 0.f}; acc2[i][jn] = z; }
  int rdw[3][3];
#pragma unroll
  for (int i = 0; i < 3; i++) {
    if (i >= mcnt) continue;
    int mr = ((m0 + i) << 4) + (lane & 15);
    rdw[i][0] = prevs[mr];
    rdw[i][1] = mr;
    rdw[i][2] = nexts[mr];
  }
  const uint4* Bg = (const uint4*)p.Bp[seg];
  for (int kc = 0; kc < 6; kc++) {
    int w_ = kc >> 1;
    int chunk = ((kc & 1) << 2) + (lane >> 4);
    HU ak[2], xv[3];
#pragma unroll
    for (int jn = 0; jn < 2; jn++)
      ak[jn].u = Bg[((wave_n * 2 + jn) * 6 + kc) * 64 + lane];
#pragma unroll
    for (int i = 0; i < 3; i++)
      if (i < mcnt) xv[i].u = xn4[rdw[i][w_] * 9 + chunk];
#pragma unroll
    for (int i = 0; i < 3; i++)
      if (i < mcnt) {
#pragma unroll
        for (int jn = 0; jn < 2; jn++)
          acc2[i][jn] = __builtin_amdgcn_mfma_f32_16x16x32_f16(ak[jn].h, xv[i].h, acc2[i][jn], 0, 0, 0);
      }
  }
  __syncthreads();  // conv reads of xn4 complete before overwrite
  // epilogue 2: final = xn + relu(conv + Kb), owner-lane RMW in LDS
#pragma unroll
  for (int i = 0; i < 3; i++) {
    if (i >= mcnt) continue;
    int r = ((m0 + i) << 4) + (lane & 15);
#pragma unroll
    for (int jn = 0; jn < 2; jn++) {
      int chq = wave_n * 32 + jn * 16 + ((lane >> 4) << 2);
      f16* pxl = xnh + r * 72 + chq;
      half4 old = *(half4*)pxl;
      half4 nv;
#pragma unroll
      for (int reg = 0; reg < 4; reg++) {
        float v = acc2[i][jn][reg] + kbl[chq + reg];
        v = v > 0.f ? v : 0.f;
        nv[reg] = (f16)((float)old[reg] + v);
      }
      *(half4*)pxl = nv;
    }
  }
  __syncthreads();
  // coalesced copy-out
  for (int idx = t; idx < R * 8; idx += 256)
    xg[idx] = xn4[(idx >> 3) * 9 + (idx & 7)];
}

// ---------------- p2a apply v2: CSR gather (no atomics); edge loop unrolled x4 --------

struct Apply2Params {
  const f16* xp[3];
  const int* cnt[3];
  const int* basea[3];
  const int* bucket;
  const f16* Wp[3];
  const float* bias[3];
  int nm;
};

__global__ __launch_bounds__(256) void k_apply2(Apply2Params p, f16* x) {
  __shared__ uint4 Af[512];
  __shared__ float bl[64];
  int t = threadIdx.x;
  int a0 = blockIdx.x * 64;
  int lane = t & 63, wid = t >> 6;
  int al = t >> 2, q = t & 3;
  int atom = a0 + al;
  f32x4 addv[4];
#pragma unroll
  for (int nt = 0; nt < 4; nt++) { f32x4 z = {0.f, 0.f, 0.f, 0.f}; addv[nt] = z; }
  for (int mi = 0; mi < p.nm; mi++) {
    __syncthreads();
    if (t < 64) bl[t] = p.bias[mi][t];
    float s[16];
#pragma unroll
    for (int i = 0; i < 16; i++) s[i] = 0.f;
    int cb = 0, base = 0;
    if (atom < NA) { cb = p.cnt[mi][atom]; base = p.basea[mi][atom]; }
    const uint4* xpu = (const uint4*)p.xp[mi];
    int i = 0;
    for (; i + 4 <= cb; i += 4) {
      int e0 = p.bucket[base + i], e1 = p.bucket[base + i + 1];
      int e2 = p.bucket[base + i + 2], e3 = p.bucket[base + i + 3];
      HU va0, vb0, va1, vb1, va2, vb2, va3, vb3;
      va0.u = xpu[(long)e0 * 8 + q * 2]; vb0.u = xpu[(long)e0 * 8 + q * 2 + 1];
      va1.u = xpu[(long)e1 * 8 + q * 2]; vb1.u = xpu[(long)e1 * 8 + q * 2 + 1];
      va2.u = xpu[(long)e2 * 8 + q * 2]; vb2.u = xpu[(long)e2 * 8 + q * 2 + 1];
      va3.u = xpu[(long)e3 * 8 + q * 2]; vb3.u = xpu[(long)e3 * 8 + q * 2 + 1];
#pragma unroll
      for (int j = 0; j < 8; j++) {
        s[j] += ((float)va0.s[j] + (float)va1.s[j]) + ((float)va2.s[j] + (float)va3.s[j]);
        s[8 + j] += ((float)vb0.s[j] + (float)vb1.s[j]) + ((float)vb2.s[j] + (float)vb3.s[j]);
      }
    }
    for (; i < cb; i++) {
      int e = p.bucket[base + i];
      HU v0, v1;
      v0.u = xpu[(long)e * 8 + q * 2];
      v1.u = xpu[(long)e * 8 + q * 2 + 1];
#pragma unroll
      for (int j = 0; j < 8; j++) { s[j] += (float)v0.s[j]; s[8 + j] += (float)v1.s[j]; }
    }
    float inv = 1.f / (float)(cb > 0 ? cb : 1);
    HU o0, o1;
#pragma unroll
    for (int j = 0; j < 8; j++) { o0.s[j] = (f16)(s[j] * inv); o1.s[j] = (f16)(s[8 + j] * inv); }
    int jb = ((al >> 4) * 2 + (q >> 1)) * 64 + (q & 1) * 32 + (al & 15);
    Af[jb] = o0.u;
    Af[jb + 16] = o1.u;
    __syncthreads();
    HU af0, af1;
    af0.u = Af[((wid << 1) + 0) * 64 + lane];
    af1.u = Af[((wid << 1) + 1) * 64 + lane];
    const uint4* Wu = (const uint4*)p.Wp[mi];
#pragma unroll
    for (int nt = 0; nt < 4; nt++) {
      HU b0, b1;
      b0.u = Wu[((nt << 1) + 0) * 64 + lane];
      b1.u = Wu[((nt << 1) + 1) * 64 + lane];
      float bv = bl[nt * 16 + (lane & 15)];
      f32x4 z = {bv, bv, bv, bv};
      z = __builtin_amdgcn_mfma_f32_16x16x32_f16(af0.h, b0.h, z, 0, 0, 0);
      z = __builtin_amdgcn_mfma_f32_16x16x32_f16(af1.h, b1.h, z, 0, 0, 0);
#pragma unroll
      for (int r = 0; r < 4; r++) {
        float vv = z[r];
        addv[nt][r] += vv > 0.f ? vv : 0.f;
      }
    }
  }
  int rowb = a0 + wid * 16 + ((lane >> 4) << 2);
#pragma unroll
  for (int nt = 0; nt < 4; nt++) {
    int n = nt * 16 + (lane & 15);
#pragma unroll
    for (int r = 0; r < 4; r++) {
      int atomw = rowb + r;
      if (atomw < NA) {
        long oi = (long)atomw * 64 + n;
        x[oi] = (f16)((float)x[oi] + addv[nt][r]);
      }
    }
  }
}

// ---------------- batch mean over f16 x ----------------

__global__ __launch_bounds__(256) void k_meanscatter(const f16* src, const int* bucket,
                                                     const int* basea, const int* cnta,
                                                     float* dst, int nseg) {
  int wid = (blockIdx.x * 256 + threadIdx.x) >> 6;
  int lane = threadIdx.x & 63;
  if (wid >= nseg) return;
  int b0 = basea[wid], cnt = cnta[wid];
  float s = 0.f;
  for (int i = 0; i < cnt; i++) {
    int e = bucket[b0 + i];
    s += (float)src[(long)e * 64 + lane];
  }
  dst[(long)wid * 64 + lane] = s / (float)(cnt > 0 ? cnt : 1);
}

// ---------------- head gemm ----------------

__global__ __launch_bounds__(256) void k_head(const float* g1, const float* W,
                                              const float* bias, float* g2) {
  __shared__ float Wl[4096];
  __shared__ float inl[32 * 64];
  __shared__ float bl[64];
  int t = threadIdx.x;
  int brow = blockIdx.x * 32;
#pragma unroll
  for (int i = 0; i < 4; i++) ((float4*)Wl)[t + 256 * i] = ((const float4*)W)[t + 256 * i];
  if (t < 64) bl[t] = bias[t];
  __syncthreads();
#pragma unroll
  for (int i = 0; i < 2; i++) {
    int idx = t + 256 * i;
    int r = idx >> 4, q = idx & 15;
    ((float4*)inl)[idx] = ((const float4*)(g1 + (long)(brow + r) * 64))[q];
  }
  __syncthreads();
  int c = t & 63, rq = t >> 6;
  float acc[8];
#pragma unroll
  for (int i = 0; i < 8; i++) acc[i] = 0.f;
  for (int j = 0; j < 64; j += 4) {
    float w0 = Wl[(j + 0) * 64 + c], w1 = Wl[(j + 1) * 64 + c];
    float w2 = Wl[(j + 2) * 64 + c], w3 = Wl[(j + 3) * 64 + c];
#pragma unroll
    for (int i = 0; i < 8; i++) {
      int r = rq * 8 + i;
      float4 v = *(const float4*)&inl[r * 64 + j];
      acc[i] += v.x * w0 + v.y * w1 + v.z * w2 + v.w * w3;
    }
  }
#pragma unroll
  for (int i = 0; i < 8; i++) {
    long r = brow + rq * 8 + i;
    float v = acc[i] + bl[c];
    g2[r * 64 + c] = v > 0.f ? v : 0.f;
  }
}

__global__ __launch_bounds__(256) void k_final(const float* g2, const float* linW,
                                               const float* linb, float* out) {
  int wid = (blockIdx.x * 256 + threadIdx.x) >> 6;
  int lane = threadIdx.x & 63;
  if (wid >= NBATCH) return;
  float v = g2[(long)wid * 64 + lane] * linW[lane];
  for (int o = 32; o > 0; o >>= 1) v += __shfl_down(v, o, 64);
  if (lane == 0) out[wid] = v + linb[0];
}

__global__ __launch_bounds__(256) void k_zero_out(float* out, int n) {
  for (int i = blockIdx.x * 256 + threadIdx.x; i < n; i += gridDim.x * 256) out[i] = 0.f;
}

// ---------------- launcher ----------------

extern "C" void kernel_launch(void* const* d_in, const int* in_sizes, int n_in,
                              void* d_out, int out_size, void* d_ws, size_t ws_size,
                              hipStream_t stream) {
  (void)in_sizes; (void)n_in;

  const int* x_atom = (const int*)d_in[0];
  const int* vals[5] = {(const int*)d_in[1], (const int*)d_in[4], (const int*)d_in[7],
                        (const int*)d_in[10], (const int*)d_in[13]};
  const int* rowm[5] = {(const int*)d_in[2], (const int*)d_in[5], (const int*)d_in[8],
                        (const int*)d_in[11], (const int*)d_in[14]};
  const int* batch = (const int*)d_in[16];
  const float* aemb0 = (const float*)d_in[17];
  const float* aemb1 = (const float*)d_in[18];
  const float* aemb2 = (const float*)d_in[19];
  const float* path_emb = (const float*)d_in[20];
  const float* cycle_emb = (const float*)d_in[21];
  const float* pW_a2p = (const float*)d_in[22];
  const float* pb_a2p = (const float*)d_in[23];
  const float* pW_p2a = (const float*)d_in[24];
  const float* pb_p2a = (const float*)d_in[25];
  const float* pK = (const float*)d_in[26];
  const float* pKb = (const float*)d_in[27];
  const float* cW_a2p = (const float*)d_in[28];
  const float* cb_a2p = (const float*)d_in[29];
  const float* cW_p2a = (const float*)d_in[30];
  const float* cb_p2a = (const float*)d_in[31];
  const float* cK = (const float*)d_in[32];
  const float* cKb = (const float*)d_in[33];
  const float* alW = (const float*)d_in[34];
  const float* alb = (const float*)d_in[35];
  const float* linW = (const float*)d_in[36];
  const float* linb = (const float*)d_in[37];

  static const int Em[5] = {300000, 400000, 500000, 200000, 240000};
  static const int Km[5] = {3, 4, 5, 5, 6};
  static const int Ppb[5] = {32, 24, 16, 16, 16};
  const int CNT_N = 5 * 100000 + NBATCH;  // 504096
  const int BUCKET_N = 1640000 + NA;      // 1740000

  char* ws = (char*)d_ws;
  size_t off = 0;
  auto alloc = [&](size_t nbytes) -> char* {
    char* p = ws + off;
    off = (off + nbytes + 255) & ~(size_t)255;
    return p;
  };
  f16* x = (f16*)alloc((size_t)NA * 64 * 2);   // f16 master
  __half* xp[5];
  for (int m = 0; m < 5; m++) xp[m] = (__half*)alloc((size_t)Em[m] * 64 * 2);
  float* g1 = (float*)alloc((size_t)NBATCH * 64 * 4);
  float* g2 = (float*)alloc((size_t)NBATCH * 64 * 4);
  int* cnt = (int*)alloc((size_t)CNT_N * 4);
  int* basea = (int*)alloc((size_t)CNT_N * 4);
  int* bucket = (int*)alloc((size_t)BUCKET_N * 4);
  unsigned* ccursor = (unsigned*)alloc((size_t)NBIN * 4);
  unsigned* cbase = (unsigned*)alloc((size_t)NBIN * 4);
  f16* Bp = (f16*)alloc((size_t)10 * 12288 * 2);
  f16* Wpk = (f16*)alloc((size_t)20 * 4096 * 2);
  f16* Tabs = (f16*)alloc((size_t)1664 * 2);
  // pairs array (~14 MB) aliases xp[2]: consumed by k_passB before k_fused writes xp[2].
  unsigned* pairs = (unsigned*)xp[2];

  if (ws_size < off) {
    k_zero_out<<<16, 256, 0, stream>>>((float*)d_out, out_size);
    return;
  }

  // ---- merged prep (atom_init + prepB + prepW + prepT + initc)
  {
    PrepParams q;
    q.xa = x_atom; q.e0 = aemb0; q.e1 = aemb1; q.e2 = aemb2; q.x = x;
    q.pK = pK; q.cK = cK; q.Bp = Bp;
    q.pW = pW_p2a; q.cW = cW_p2a; q.pWa = pW_a2p; q.cWa = cW_a2p; q.Wp = Wpk;
    q.path_emb = path_emb; q.cycle_emb = cycle_emb; q.T = Tabs;
    q.ccursor = ccursor;
    k_prep<<<7058, 256, 0, stream>>>(q);
  }

  // ---- CSR build: two-level counting sort
  PassAParams pp;
  {
    int s = 0;
    for (int m = 0; m < 5; m++) { pp.row[m] = rowm[m]; pp.start[m] = s; s += Em[m]; }
    pp.row[5] = batch; pp.start[5] = s;
    pp.total = s + NA;  // 1740000
  }
  k_passA<<<(1740000 + 8191) / 8192, 256, 0, stream>>>(pp, ccursor, pairs);
  k_cscan<<<1, 256, 0, stream>>>(ccursor, cbase);
  k_passB<<<NBIN, 256, 0, stream>>>(ccursor, cbase, pairs, bucket, cnt, basea);

  int apply_blocks = (NA + 63) / 64;  // 1563

  auto p2aW = [&](int l, int m) -> const f16* {
    return (m < 3) ? Wpk + (size_t)(l * 3 + m) * 4096
                   : Wpk + (size_t)(6 + l * 2 + (m - 3)) * 4096;
  };
  auto p2aB = [&](int l, int m) -> const float* {
    return (m < 3) ? pb_p2a + (l * 3 + m) * 64 : cb_p2a + (l * 2 + (m - 3)) * 64;
  };

  for (int l = 0; l < 2; l++) {
    // === paths group (maps 0..2), non-cyclic
    {
      FusedParams fp{};
      fp.nseg = 3; fp.cyclic = 0; fp.xh = x; fp.use_tab = (l == 0) ? 1 : 0;
      int bs = 0;
      for (int m = 0; m < 3; m++) {
        fp.gidx[m] = rowm[m]; fp.xp[m] = xp[m];
        fp.vals[m] = vals[m]; fp.tab[m] = Tabs + (size_t)m * 384;
        fp.Wa[m] = Wpk + (size_t)(10 + l * 3 + m) * 4096;
        fp.ba[m] = pb_a2p + (l * 3 + m) * 64;
        fp.Bp[m] = Bp + (size_t)(l * 3 + m) * 12288;
        fp.Kb[m] = pKb + (l * 3 + m) * 64;
        fp.k[m] = Km[m]; fp.P[m] = Em[m] / Km[m]; fp.ppb[m] = Ppb[m];
        fp.blk_start[m] = bs;
        bs += (fp.P[m] + fp.ppb[m] - 1) / fp.ppb[m];
      }
      k_fused<<<bs, 256, 0, stream>>>(fp);

      Apply2Params ap{};
      ap.nm = 3; ap.bucket = bucket;
      for (int m = 0; m < 3; m++) {
        ap.xp[m] = (const f16*)xp[m];
        ap.cnt[m] = cnt + (size_t)m * 100000;
        ap.basea[m] = basea + (size_t)m * 100000;
        ap.Wp[m] = p2aW(l, m); ap.bias[m] = p2aB(l, m);
      }
      k_apply2<<<apply_blocks, 256, 0, stream>>>(ap, x);
    }
    // === cycles group (maps 3..4), cyclic
    {
      FusedParams fp{};
      fp.nseg = 2; fp.cyclic = 1; fp.xh = x; fp.use_tab = (l == 0) ? 1 : 0;
      int bs = 0;
      for (int m = 3; m < 5; m++) {
        int i = m - 3;
        fp.gidx[i] = rowm[m]; fp.xp[i] = xp[m];
        fp.vals[i] = vals[m]; fp.tab[i] = Tabs + 1152 + (size_t)i * 256;
        fp.Wa[i] = Wpk + (size_t)(16 + l * 2 + i) * 4096;
        fp.ba[i] = cb_a2p + (l * 2 + i) * 64;
        fp.Bp[i] = Bp + (size_t)(6 + l * 2 + i) * 12288;
        fp.Kb[i] = cKb + (l * 2 + i) * 64;
        fp.k[i] = Km[m]; fp.P[i] = Em[m] / Km[m]; fp.ppb[i] = Ppb[m];
        fp.blk_start[i] = bs;
        bs += (fp.P[i] + fp.ppb[i] - 1) / fp.ppb[i];
      }
      k_fused<<<bs, 256, 0, stream>>>(fp);

      Apply2Params ap{};
      ap.nm = 2; ap.bucket = bucket;
      for (int m = 3; m < 5; m++) {
        int i = m - 3;
        ap.xp[i] = (const f16*)xp[m];
        ap.cnt[i] = cnt + (size_t)m * 100000;
        ap.basea[i] = basea + (size_t)m * 100000;
        ap.Wp[i] = p2aW(l, m); ap.bias[i] = p2aB(l, m);
      }
      k_apply2<<<apply_blocks, 256, 0, stream>>>(ap, x);
    }
  }

  // ---- head (basea entries for the batch segment are GLOBAL bucket positions)
  k_meanscatter<<<NBATCH / 4, 256, 0, stream>>>(x, bucket, basea + 500000,
                                                cnt + 500000, g1, NBATCH);
  k_head<<<NBATCH / 32, 256, 0, stream>>>(g1, alW, alb, g2);
  k_final<<<NBATCH / 4, 256, 0, stream>>>(g2, linW, linb, (float*)d_out);
}

// Round 7
// 710.792 us; speedup vs baseline: 1.0984x; 1.0084x over previous
//
#include <hip/hip_runtime.h>
#include <hip/hip_fp16.h>

#define NA 100000
#define NBATCH 4096
#define NBIN 1971       // 5 maps * 391 atom-ranges + 16 batch-ranges
#define MAPS_BINS 1955  // 5 * 391

typedef _Float16 f16;
typedef f16 half8 __attribute__((ext_vector_type(8)));
typedef f16 half4 __attribute__((ext_vector_type(4)));
typedef float f32x4 __attribute__((ext_vector_type(4)));
union HU { uint4 u; half8 h; f16 s[8]; };

// ---------------- two-level counting sort CSR build ----------------
__device__ __forceinline__ unsigned capbase_of(int b) {
  if (b < 391)  return 0u       + (unsigned)(b       ) * 1536u;
  if (b < 782)  return 600576u  + (unsigned)(b -  391) * 2048u;
  if (b < 1173) return 1401344u + (unsigned)(b -  782) * 2560u;
  if (b < 1564) return 2402304u + (unsigned)(b - 1173) * 1024u;
  if (b < 1955) return 2802688u + (unsigned)(b - 1564) * 1232u;
  return 3284400u + (unsigned)(b - 1955) * 12500u;
}

struct PassAParams {
  const int* row[6];
  int start[6];
  int total;
};

__global__ __launch_bounds__(256) void k_passA(PassAParams pp, unsigned* ccursor,
                                               unsigned* pairs) {
  __shared__ int hist[NBIN];
  __shared__ unsigned hbase[NBIN];
  int t = threadIdx.x;
  for (int b = t; b < NBIN; b += 256) hist[b] = 0;
  __syncthreads();
  int g0 = blockIdx.x * 8192;
  unsigned keys[32];
#pragma unroll
  for (int i = 0; i < 32; i++) {
    int g = g0 + i * 256 + t;
    keys[i] = 0xFFFFFFFFu;
    if (g < pp.total) {
      int m = 0;
#pragma unroll
      for (int j = 1; j < 6; j++) if (g >= pp.start[j]) m = j;
      int e = g - pp.start[m];
      int a = pp.row[m][e];
      int bin = (m < 5) ? m * 391 + (a >> 8) : MAPS_BINS + (a >> 8);
      keys[i] = ((unsigned)bin << 8) | (unsigned)(a & 255);
      atomicAdd(&hist[bin], 1);
    }
  }
  __syncthreads();
  for (int b = t; b < NBIN; b += 256) {
    int h = hist[b];
    hbase[b] = h ? atomicAdd(&ccursor[b], (unsigned)h) : 0u;
  }
  __syncthreads();
#pragma unroll
  for (int i = 0; i < 32; i++) {
    unsigned kv = keys[i];
    if (kv == 0xFFFFFFFFu) continue;
    int bin = (int)(kv >> 8);
    int g = g0 + i * 256 + t;
    int m = 0;
#pragma unroll
    for (int j = 1; j < 6; j++) if (g >= pp.start[j]) m = j;
    int e = g - pp.start[m];
    unsigned pos = atomicAdd(&hbase[bin], 1u);
    pairs[pos] = ((unsigned)e << 8) | (kv & 255u);
  }
}

__global__ __launch_bounds__(256) void k_cscan(const unsigned* ccursor, unsigned* cbase) {
  __shared__ unsigned s[256];
  int t = threadIdx.x;
  unsigned carry = 0;
  for (int c0 = 0; c0 < NBIN; c0 += 256) {
    int b = c0 + t;
    unsigned v = 0;
    if (b < NBIN) v = ccursor[b] - capbase_of(b);
    s[t] = v;
    __syncthreads();
    for (int d = 1; d < 256; d <<= 1) {
      unsigned x = (t >= d) ? s[t - d] : 0;
      __syncthreads();
      s[t] += x;
      __syncthreads();
    }
    if (b < NBIN) cbase[b] = s[t] - v + carry;
    unsigned tot = s[255];
    __syncthreads();
    carry += tot;
  }
}

__global__ __launch_bounds__(256) void k_passB(const unsigned* ccursor, const unsigned* cbase,
                                               const unsigned* pairs, int* bucket,
                                               int* cnt, int* basea) {
  __shared__ int hist[256];
  __shared__ int scn[256];
  __shared__ unsigned cur[256];
  int b = blockIdx.x;
  int t = threadIdx.x;
  unsigned cb0 = capbase_of(b);
  int count = (int)(ccursor[b] - cb0);
  const unsigned* src = pairs + cb0;
  hist[t] = 0;
  __syncthreads();
  for (int i = t; i < count; i += 256) atomicAdd(&hist[src[i] & 255u], 1);
  __syncthreads();
  int h = hist[t];
  scn[t] = h;
  __syncthreads();
  for (int d = 1; d < 256; d <<= 1) {
    int x = (t >= d) ? scn[t - d] : 0;
    __syncthreads();
    scn[t] += x;
    __syncthreads();
  }
  int excl = scn[t] - h;
  unsigned gbase = cbase[b];
  int m, a0, off, amax;
  if (b < MAPS_BINS) { m = b / 391; a0 = (b - m * 391) << 8; off = m * 100000; amax = 100000; }
  else { m = 5; a0 = (b - MAPS_BINS) << 8; off = 500000; amax = NBATCH; }
  if (a0 + t < amax) {
    cnt[off + a0 + t] = h;
    basea[off + a0 + t] = (int)(gbase + (unsigned)excl);
  }
  cur[t] = gbase + (unsigned)excl;
  __syncthreads();
  for (int i = t; i < count; i += 256) {
    unsigned v = src[i];
    unsigned pos = atomicAdd(&cur[v & 255u], 1u);
    bucket[pos] = (int)(v >> 8);
  }
}

// ---------------- merged prep kernel: atom_init + prepB + prepW + prepT + initc --------

struct PrepParams {
  const int* xa; const float *e0; const float *e1; const float *e2; f16* x;
  const float *pK; const float *cK; f16* Bp;
  const float *pW; const float *cW; const float *pWa; const float *cWa; f16* Wp;
  const float *path_emb; const float *cycle_emb; f16* T;
  unsigned* ccursor;
};

__global__ __launch_bounds__(256) void k_prep(PrepParams q) {
  int bid = blockIdx.x, t = threadIdx.x;
  if (bid < 6250) {
    int idx = bid * 256 + t;
    int a = idx >> 4, qq = idx & 15;
    int f0 = q.xa[a * 3], f1 = q.xa[a * 3 + 1], f2 = q.xa[a * 3 + 2];
    float4 v0 = ((const float4*)q.e0)[f0 * 16 + qq];
    float4 v1 = ((const float4*)q.e1)[f1 * 16 + qq];
    float4 v2 = ((const float4*)q.e2)[f2 * 16 + qq];
    half4 h = {(f16)(v0.x + v1.x + v2.x), (f16)(v0.y + v1.y + v2.y),
               (f16)(v0.z + v1.z + v2.z), (f16)(v0.w + v1.w + v2.w)};
    ((half4*)q.x)[idx] = h;
  } else if (bid < 6730) {
    int tid = (bid - 6250) * 256 + t;
    int set = tid / 12288, pos = tid % 12288;
    int j = pos & 7, lane = (pos >> 3) & 63, kcnt = pos >> 9;
    int kc = kcnt % 6, nt = kcnt / 6;
    int k = kc * 32 + ((lane >> 4) << 3) + j;
    int n = (nt << 4) + (lane & 15);
    int w = k >> 6, ji = k & 63;
    const float* K = (set < 6) ? (q.pK + set * 3 * 4096) : (q.cK + (set - 6) * 3 * 4096);
    float v = K[w * 4096 + ji * 64 + n];
    if (set >= 6) v = 0.5f * (v + K[(2 - w) * 4096 + ji * 64 + n]);
    q.Bp[tid] = (f16)v;
  } else if (bid < 7050) {
    int tid = (bid - 6730) * 256 + t;
    int set = tid >> 12, pos = tid & 4095;
    int j = pos & 7, lane = (pos >> 3) & 63, ntkc = pos >> 9;
    int kc = ntkc & 1, nt = ntkc >> 1;
    int k = kc * 32 + ((lane >> 4) << 3) + j;
    int n = (nt << 4) + (lane & 15);
    const float* W;
    if (set < 6) W = q.pW + set * 4096;
    else if (set < 10) W = q.cW + (set - 6) * 4096;
    else if (set < 16) W = q.pWa + (set - 10) * 4096;
    else W = q.cWa + (set - 16) * 4096;
    q.Wp[tid] = (f16)W[k * 64 + n];
  } else {
    int idx = (bid - 7050) * 256 + t;
    if (idx < 1664) {
      float v = (idx < 1152) ? q.path_emb[idx] : q.cycle_emb[idx - 1152];
      q.T[idx] = (f16)v;
    }
    if (idx < NBIN) q.ccursor[idx] = capbase_of(idx);
  }
}

// ---------------- fused a2p+conv (swapped-operand MFMA) ----------------
// R6-proven skeleton (interleaved gathers, 4 barriers, coalesced copy-out).
// New this round: bias via MFMA acc-init + packed-f16 residual add in epilogues
// (per half4: 4 max + 4 cvt + 2 v_pk_add_f16 vs 20 scalar ops before).

struct FusedParams {
  const f16* xh;
  const int* gidx[3];
  const int* vals[3];
  const f16* tab[3];
  __half* xp[3];
  const f16* Wa[3];
  const float* ba[3];
  const f16* Bp[3];
  const float* Kb[3];
  int k[3];
  int P[3];
  int ppb[3];
  int blk_start[3];
  int nseg;
  int cyclic;
  int use_tab;
};

__global__ __launch_bounds__(256) void k_fused(FusedParams p) {
  __shared__ uint4 xn4[873];     // 97 rows x 9 uint4 (72 f16/row, row 96 = zero pad)
  __shared__ float bl[64], kbl[64];
  __shared__ int ridx[96];
  __shared__ short prevs[96], nexts[96];
  int bid = blockIdx.x;
  int seg = 0;
#pragma unroll
  for (int i = 1; i < 3; i++) if (i < p.nseg && bid >= p.blk_start[i]) seg = i;
  int kk = p.k[seg], ppb = p.ppb[seg], P = p.P[seg];
  int cyc = p.cyclic;
  int t = threadIdx.x;
  int p0 = (bid - p.blk_start[seg]) * ppb;
  int np = min(ppb, P - p0);
  int R = np * kk;    // always a multiple of 16 for these ppb choices
  int mtb = R >> 4;
  long ebase = (long)p0 * kk;
  if (t < 64) { bl[t] = p.ba[seg][t]; kbl[t] = p.Kb[seg][t]; }
  if (t < 9) { uint4 z; z.x = z.y = z.z = z.w = 0; xn4[96 * 9 + t] = z; }
  if (t < R) ridx[t] = p.gidx[seg][ebase + t];
  if (t < 96) {
    int sm = t % kk;
    prevs[t] = (short)((sm >= 1) ? t - 1 : (cyc ? t + kk - 1 : 96));
    nexts[t] = (short)((sm + 1 < kk) ? t + 1 : (cyc ? t + 1 - kk : 96));
  }
  uint4* xg = (uint4*)(p.xp[seg] + (long)ebase * 64);
  if (p.use_tab) {
    const uint4* tabu = (const uint4*)p.tab[seg];
    const int* vseg = p.vals[seg];
    for (int idx = t; idx < R * 8; idx += 256) {
      int row = idx >> 3, ch = idx & 7;
      xn4[row * 9 + ch] = tabu[vseg[ebase + row] * 8 + ch];
    }
  } else {
    for (int idx = t; idx < R * 8; idx += 256)
      xn4[(idx >> 3) * 9 + (idx & 7)] = xg[idx];
  }
  __syncthreads();
  int lane = t & 63, wid = t >> 6;
  int wave_n = wid & 1, wave_m = wid >> 1;
  int mtA = (mtb + 1) >> 1;
  int m0 = wave_m ? mtA : 0;
  int mcnt = wave_m ? (mtb - mtA) : mtA;
  f16* xnh = (f16*)xn4;
  int chq0 = wave_n * 32 + ((lane >> 4) << 2);   // jn=0 channel quad
  int chq1 = chq0 + 16;                           // jn=1 channel quad
  // stage A: xn += relu(x_gather @ Wa + ba)  (bias via acc init; pk-f16 residual add)
  {
    f32x4 b0 = {bl[chq0], bl[chq0 + 1], bl[chq0 + 2], bl[chq0 + 3]};
    f32x4 b1 = {bl[chq1], bl[chq1 + 1], bl[chq1 + 2], bl[chq1 + 3]};
    f32x4 acc1[3][2];
#pragma unroll
    for (int i = 0; i < 3; i++) { acc1[i][0] = b0; acc1[i][1] = b1; }
    const uint4* Wau = (const uint4*)p.Wa[seg];
    HU w[2][2];
#pragma unroll
    for (int kc = 0; kc < 2; kc++)
#pragma unroll
      for (int jn = 0; jn < 2; jn++)
        w[kc][jn].u = Wau[(((wave_n * 2 + jn) << 1) + kc) * 64 + lane];
    const uint4* xh4 = (const uint4*)p.xh;
#pragma unroll
    for (int i = 0; i < 3; i++) {
      if (i >= mcnt) continue;
      int rowid = ridx[((m0 + i) << 4) + (lane & 15)];
      HU xa, xb;
      xa.u = xh4[(long)rowid * 8 + (lane >> 4)];
      xb.u = xh4[(long)rowid * 8 + 4 + (lane >> 4)];
#pragma unroll
      for (int jn = 0; jn < 2; jn++) {
        acc1[i][jn] = __builtin_amdgcn_mfma_f32_16x16x32_f16(w[0][jn].h, xa.h, acc1[i][jn], 0, 0, 0);
        acc1[i][jn] = __builtin_amdgcn_mfma_f32_16x16x32_f16(w[1][jn].h, xb.h, acc1[i][jn], 0, 0, 0);
      }
    }
#pragma unroll
    for (int i = 0; i < 3; i++) {
      if (i >= mcnt) continue;
      int r = ((m0 + i) << 4) + (lane & 15);
#pragma unroll
      for (int jn = 0; jn < 2; jn++) {
        int chq = jn ? chq1 : chq0;
        half4 cv;
#pragma unroll
        for (int reg = 0; reg < 4; reg++) {
          float v = acc1[i][jn][reg];
          cv[reg] = (f16)(v > 0.f ? v : 0.f);
        }
        half4* pxl = (half4*)(xnh + r * 72 + chq);
        *pxl = *pxl + cv;   // v_pk_add_f16 x2
      }
    }
  }
  __syncthreads();
  // conv MFMAs reading xn4 (neighbor rows via LDS tables); bias via acc init
  f32x4 k0 = {kbl[chq0], kbl[chq0 + 1], kbl[chq0 + 2], kbl[chq0 + 3]};
  f32x4 k1 = {kbl[chq1], kbl[chq1 + 1], kbl[chq1 + 2], kbl[chq1 + 3]};
  f32x4 acc2[3][2];
#pragma unroll
  for (int i = 0; i < 3; i++) { acc2[i][0] = k0; acc2[i][1] = k1; }
  int rdw[3][3];
#pragma unroll
  for (int i = 0; i < 3; i++) {
    if (i >= mcnt) continue;
    int mr = ((m0 + i) << 4) + (lane & 15);
    rdw[i][0] = prevs[mr];
    rdw[i][1] = mr;
    rdw[i][2] = nexts[mr];
  }
  const uint4* Bg = (const uint4*)p.Bp[seg];
  for (int kc = 0; kc < 6; kc++) {
    int w_ = kc >> 1;
    int chunk = ((kc & 1) << 2) + (lane >> 4);
    HU ak[2], xv[3];
#pragma unroll
    for (int jn = 0; jn < 2; jn++)
      ak[jn].u = Bg[((wave_n * 2 + jn) * 6 + kc) * 64 + lane];
#pragma unroll
    for (int i = 0; i < 3; i++)
      if (i < mcnt) xv[i].u = xn4[rdw[i][w_] * 9 + chunk];
#pragma unroll
    for (int i = 0; i < 3; i++)
      if (i < mcnt) {
#pragma unroll
        for (int jn = 0; jn < 2; jn++)
          acc2[i][jn] = __builtin_amdgcn_mfma_f32_16x16x32_f16(ak[jn].h, xv[i].h, acc2[i][jn], 0, 0, 0);
      }
  }
  __syncthreads();  // conv reads of xn4 complete before overwrite
  // epilogue 2: final = xn + relu(conv + Kb), pk-f16 RMW in LDS
#pragma unroll
  for (int i = 0; i < 3; i++) {
    if (i >= mcnt) continue;
    int r = ((m0 + i) << 4) + (lane & 15);
#pragma unroll
    for (int jn = 0; jn < 2; jn++) {
      int chq = jn ? chq1 : chq0;
      half4 cv;
#pragma unroll
      for (int reg = 0; reg < 4; reg++) {
        float v = acc2[i][jn][reg];
        cv[reg] = (f16)(v > 0.f ? v : 0.f);
      }
      half4* pxl = (half4*)(xnh + r * 72 + chq);
      *pxl = *pxl + cv;
    }
  }
  __syncthreads();
  // coalesced copy-out
  for (int idx = t; idx < R * 8; idx += 256)
    xg[idx] = xn4[(idx >> 3) * 9 + (idx & 7)];
}

// ---------------- p2a apply v2: CSR gather (no atomics); edge loop unrolled x4 --------

struct Apply2Params {
  const f16* xp[3];
  const int* cnt[3];
  const int* basea[3];
  const int* bucket;
  const f16* Wp[3];
  const float* bias[3];
  int nm;
};

__global__ __launch_bounds__(256) void k_apply2(Apply2Params p, f16* x) {
  __shared__ uint4 Af[512];
  __shared__ float bl[64];
  int t = threadIdx.x;
  int a0 = blockIdx.x * 64;
  int lane = t & 63, wid = t >> 6;
  int al = t >> 2, q = t & 3;
  int atom = a0 + al;
  f32x4 addv[4];
#pragma unroll
  for (int nt = 0; nt < 4; nt++) { f32x4 z = {0.f, 0.f, 0.f, 0.f}; addv[nt] = z; }
  for (int mi = 0; mi < p.nm; mi++) {
    __syncthreads();
    if (t < 64) bl[t] = p.bias[mi][t];
    float s[16];
#pragma unroll
    for (int i = 0; i < 16; i++) s[i] = 0.f;
    int cb = 0, base = 0;
    if (atom < NA) { cb = p.cnt[mi][atom]; base = p.basea[mi][atom]; }
    const uint4* xpu = (const uint4*)p.xp[mi];
    int i = 0;
    for (; i + 4 <= cb; i += 4) {
      int e0 = p.bucket[base + i], e1 = p.bucket[base + i + 1];
      int e2 = p.bucket[base + i + 2], e3 = p.bucket[base + i + 3];
      HU va0, vb0, va1, vb1, va2, vb2, va3, vb3;
      va0.u = xpu[(long)e0 * 8 + q * 2]; vb0.u = xpu[(long)e0 * 8 + q * 2 + 1];
      va1.u = xpu[(long)e1 * 8 + q * 2]; vb1.u = xpu[(long)e1 * 8 + q * 2 + 1];
      va2.u = xpu[(long)e2 * 8 + q * 2]; vb2.u = xpu[(long)e2 * 8 + q * 2 + 1];
      va3.u = xpu[(long)e3 * 8 + q * 2]; vb3.u = xpu[(long)e3 * 8 + q * 2 + 1];
#pragma unroll
      for (int j = 0; j < 8; j++) {
        s[j] += ((float)va0.s[j] + (float)va1.s[j]) + ((float)va2.s[j] + (float)va3.s[j]);
        s[8 + j] += ((float)vb0.s[j] + (float)vb1.s[j]) + ((float)vb2.s[j] + (float)vb3.s[j]);
      }
    }
    for (; i < cb; i++) {
      int e = p.bucket[base + i];
      HU v0, v1;
      v0.u = xpu[(long)e * 8 + q * 2];
      v1.u = xpu[(long)e * 8 + q * 2 + 1];
#pragma unroll
      for (int j = 0; j < 8; j++) { s[j] += (float)v0.s[j]; s[8 + j] += (float)v1.s[j]; }
    }
    float inv = 1.f / (float)(cb > 0 ? cb : 1);
    HU o0, o1;
#pragma unroll
    for (int j = 0; j < 8; j++) { o0.s[j] = (f16)(s[j] * inv); o1.s[j] = (f16)(s[8 + j] * inv); }
    int jb = ((al >> 4) * 2 + (q >> 1)) * 64 + (q & 1) * 32 + (al & 15);
    Af[jb] = o0.u;
    Af[jb + 16] = o1.u;
    __syncthreads();
    HU af0, af1;
    af0.u = Af[((wid << 1) + 0) * 64 + lane];
    af1.u = Af[((wid << 1) + 1) * 64 + lane];
    const uint4* Wu = (const uint4*)p.Wp[mi];
#pragma unroll
    for (int nt = 0; nt < 4; nt++) {
      HU b0, b1;
      b0.u = Wu[((nt << 1) + 0) * 64 + lane];
      b1.u = Wu[((nt << 1) + 1) * 64 + lane];
      float bv = bl[nt * 16 + (lane & 15)];
      f32x4 z = {bv, bv, bv, bv};
      z = __builtin_amdgcn_mfma_f32_16x16x32_f16(af0.h, b0.h, z, 0, 0, 0);
      z = __builtin_amdgcn_mfma_f32_16x16x32_f16(af1.h, b1.h, z, 0, 0, 0);
#pragma unroll
      for (int r = 0; r < 4; r++) {
        float vv = z[r];
        addv[nt][r] += vv > 0.f ? vv : 0.f;
      }
    }
  }
  int rowb = a0 + wid * 16 + ((lane >> 4) << 2);
#pragma unroll
  for (int nt = 0; nt < 4; nt++) {
    int n = nt * 16 + (lane & 15);
#pragma unroll
    for (int r = 0; r < 4; r++) {
      int atomw = rowb + r;
      if (atomw < NA) {
        long oi = (long)atomw * 64 + n;
        x[oi] = (f16)((float)x[oi] + addv[nt][r]);
      }
    }
  }
}

// ---------------- batch mean over f16 x ----------------

__global__ __launch_bounds__(256) void k_meanscatter(const f16* src, const int* bucket,
                                                     const int* basea, const int* cnta,
                                                     float* dst, int nseg) {
  int wid = (blockIdx.x * 256 + threadIdx.x) >> 6;
  int lane = threadIdx.x & 63;
  if (wid >= nseg) return;
  int b0 = basea[wid], cnt = cnta[wid];
  float s = 0.f;
  for (int i = 0; i < cnt; i++) {
    int e = bucket[b0 + i];
    s += (float)src[(long)e * 64 + lane];
  }
  dst[(long)wid * 64 + lane] = s / (float)(cnt > 0 ? cnt : 1);
}

// ---------------- head gemm ----------------

__global__ __launch_bounds__(256) void k_head(const float* g1, const float* W,
                                              const float* bias, float* g2) {
  __shared__ float Wl[4096];
  __shared__ float inl[32 * 64];
  __shared__ float bl[64];
  int t = threadIdx.x;
  int brow = blockIdx.x * 32;
#pragma unroll
  for (int i = 0; i < 4; i++) ((float4*)Wl)[t + 256 * i] = ((const float4*)W)[t + 256 * i];
  if (t < 64) bl[t] = bias[t];
  __syncthreads();
#pragma unroll
  for (int i = 0; i < 2; i++) {
    int idx = t + 256 * i;
    int r = idx >> 4, q = idx & 15;
    ((float4*)inl)[idx] = ((const float4*)(g1 + (long)(brow + r) * 64))[q];
  }
  __syncthreads();
  int c = t & 63, rq = t >> 6;
  float acc[8];
#pragma unroll
  for (int i = 0; i < 8; i++) acc[i] = 0.f;
  for (int j = 0; j < 64; j += 4) {
    float w0 = Wl[(j + 0) * 64 + c], w1 = Wl[(j + 1) * 64 + c];
    float w2 = Wl[(j + 2) * 64 + c], w3 = Wl[(j + 3) * 64 + c];
#pragma unroll
    for (int i = 0; i < 8; i++) {
      int r = rq * 8 + i;
      float4 v = *(const float4*)&inl[r * 64 + j];
      acc[i] += v.x * w0 + v.y * w1 + v.z * w2 + v.w * w3;
    }
  }
#pragma unroll
  for (int i = 0; i < 8; i++) {
    long r = brow + rq * 8 + i;
    float v = acc[i] + bl[c];
    g2[r * 64 + c] = v > 0.f ? v : 0.f;
  }
}

__global__ __launch_bounds__(256) void k_final(const float* g2, const float* linW,
                                               const float* linb, float* out) {
  int wid = (blockIdx.x * 256 + threadIdx.x) >> 6;
  int lane = threadIdx.x & 63;
  if (wid >= NBATCH) return;
  float v = g2[(long)wid * 64 + lane] * linW[lane];
  for (int o = 32; o > 0; o >>= 1) v += __shfl_down(v, o, 64);
  if (lane == 0) out[wid] = v + linb[0];
}

__global__ __launch_bounds__(256) void k_zero_out(float* out, int n) {
  for (int i = blockIdx.x * 256 + threadIdx.x; i < n; i += gridDim.x * 256) out[i] = 0.f;
}

// ---------------- launcher ----------------

extern "C" void kernel_launch(void* const* d_in, const int* in_sizes, int n_in,
                              void* d_out, int out_size, void* d_ws, size_t ws_size,
                              hipStream_t stream) {
  (void)in_sizes; (void)n_in;

  const int* x_atom = (const int*)d_in[0];
  const int* vals[5] = {(const int*)d_in[1], (const int*)d_in[4], (const int*)d_in[7],
                        (const int*)d_in[10], (const int*)d_in[13]};
  const int* rowm[5] = {(const int*)d_in[2], (const int*)d_in[5], (const int*)d_in[8],
                        (const int*)d_in[11], (const int*)d_in[14]};
  const int* batch = (const int*)d_in[16];
  const float* aemb0 = (const float*)d_in[17];
  const float* aemb1 = (const float*)d_in[18];
  const float* aemb2 = (const float*)d_in[19];
  const float* path_emb = (const float*)d_in[20];
  const float* cycle_emb = (const float*)d_in[21];
  const float* pW_a2p = (const float*)d_in[22];
  const float* pb_a2p = (const float*)d_in[23];
  const float* pW_p2a = (const float*)d_in[24];
  const float* pb_p2a = (const float*)d_in[25];
  const float* pK = (const float*)d_in[26];
  const float* pKb = (const float*)d_in[27];
  const float* cW_a2p = (const float*)d_in[28];
  const float* cb_a2p = (const float*)d_in[29];
  const float* cW_p2a = (const float*)d_in[30];
  const float* cb_p2a = (const float*)d_in[31];
  const float* cK = (const float*)d_in[32];
  const float* cKb = (const float*)d_in[33];
  const float* alW = (const float*)d_in[34];
  const float* alb = (const float*)d_in[35];
  const float* linW = (const float*)d_in[36];
  const float* linb = (const float*)d_in[37];

  static const int Em[5] = {300000, 400000, 500000, 200000, 240000};
  static const int Km[5] = {3, 4, 5, 5, 6};
  static const int Ppb[5] = {32, 24, 16, 16, 16};
  const int CNT_N = 5 * 100000 + NBATCH;  // 504096
  const int BUCKET_N = 1640000 + NA;      // 1740000

  char* ws = (char*)d_ws;
  size_t off = 0;
  auto alloc = [&](size_t nbytes) -> char* {
    char* p = ws + off;
    off = (off + nbytes + 255) & ~(size_t)255;
    return p;
  };
  f16* x = (f16*)alloc((size_t)NA * 64 * 2);   // f16 master
  __half* xp[5];
  for (int m = 0; m < 5; m++) xp[m] = (__half*)alloc((size_t)Em[m] * 64 * 2);
  float* g1 = (float*)alloc((size_t)NBATCH * 64 * 4);
  float* g2 = (float*)alloc((size_t)NBATCH * 64 * 4);
  int* cnt = (int*)alloc((size_t)CNT_N * 4);
  int* basea = (int*)alloc((size_t)CNT_N * 4);
  int* bucket = (int*)alloc((size_t)BUCKET_N * 4);
  unsigned* ccursor = (unsigned*)alloc((size_t)NBIN * 4);
  unsigned* cbase = (unsigned*)alloc((size_t)NBIN * 4);
  f16* Bp = (f16*)alloc((size_t)10 * 12288 * 2);
  f16* Wpk = (f16*)alloc((size_t)20 * 4096 * 2);
  f16* Tabs = (f16*)alloc((size_t)1664 * 2);
  // pairs array (~14 MB) aliases xp[2]: consumed by k_passB before k_fused writes xp[2].
  unsigned* pairs = (unsigned*)xp[2];

  if (ws_size < off) {
    k_zero_out<<<16, 256, 0, stream>>>((float*)d_out, out_size);
    return;
  }

  // ---- merged prep (atom_init + prepB + prepW + prepT + initc)
  {
    PrepParams q;
    q.xa = x_atom; q.e0 = aemb0; q.e1 = aemb1; q.e2 = aemb2; q.x = x;
    q.pK = pK; q.cK = cK; q.Bp = Bp;
    q.pW = pW_p2a; q.cW = cW_p2a; q.pWa = pW_a2p; q.cWa = cW_a2p; q.Wp = Wpk;
    q.path_emb = path_emb; q.cycle_emb = cycle_emb; q.T = Tabs;
    q.ccursor = ccursor;
    k_prep<<<7058, 256, 0, stream>>>(q);
  }

  // ---- CSR build: two-level counting sort
  PassAParams pp;
  {
    int s = 0;
    for (int m = 0; m < 5; m++) { pp.row[m] = rowm[m]; pp.start[m] = s; s += Em[m]; }
    pp.row[5] = batch; pp.start[5] = s;
    pp.total = s + NA;  // 1740000
  }
  k_passA<<<(1740000 + 8191) / 8192, 256, 0, stream>>>(pp, ccursor, pairs);
  k_cscan<<<1, 256, 0, stream>>>(ccursor, cbase);
  k_passB<<<NBIN, 256, 0, stream>>>(ccursor, cbase, pairs, bucket, cnt, basea);

  int apply_blocks = (NA + 63) / 64;  // 1563

  auto p2aW = [&](int l, int m) -> const f16* {
    return (m < 3) ? Wpk + (size_t)(l * 3 + m) * 4096
                   : Wpk + (size_t)(6 + l * 2 + (m - 3)) * 4096;
  };
  auto p2aB = [&](int l, int m) -> const float* {
    return (m < 3) ? pb_p2a + (l * 3 + m) * 64 : cb_p2a + (l * 2 + (m - 3)) * 64;
  };

  for (int l = 0; l < 2; l++) {
    // === paths group (maps 0..2), non-cyclic
    {
      FusedParams fp{};
      fp.nseg = 3; fp.cyclic = 0; fp.xh = x; fp.use_tab = (l == 0) ? 1 : 0;
      int bs = 0;
      for (int m = 0; m < 3; m++) {
        fp.gidx[m] = rowm[m]; fp.xp[m] = xp[m];
        fp.vals[m] = vals[m]; fp.tab[m] = Tabs + (size_t)m * 384;
        fp.Wa[m] = Wpk + (size_t)(10 + l * 3 + m) * 4096;
        fp.ba[m] = pb_a2p + (l * 3 + m) * 64;
        fp.Bp[m] = Bp + (size_t)(l * 3 + m) * 12288;
        fp.Kb[m] = pKb + (l * 3 + m) * 64;
        fp.k[m] = Km[m]; fp.P[m] = Em[m] / Km[m]; fp.ppb[m] = Ppb[m];
        fp.blk_start[m] = bs;
        bs += (fp.P[m] + fp.ppb[m] - 1) / fp.ppb[m];
      }
      k_fused<<<bs, 256, 0, stream>>>(fp);

      Apply2Params ap{};
      ap.nm = 3; ap.bucket = bucket;
      for (int m = 0; m < 3; m++) {
        ap.xp[m] = (const f16*)xp[m];
        ap.cnt[m] = cnt + (size_t)m * 100000;
        ap.basea[m] = basea + (size_t)m * 100000;
        ap.Wp[m] = p2aW(l, m); ap.bias[m] = p2aB(l, m);
      }
      k_apply2<<<apply_blocks, 256, 0, stream>>>(ap, x);
    }
    // === cycles group (maps 3..4), cyclic
    {
      FusedParams fp{};
      fp.nseg = 2; fp.cyclic = 1; fp.xh = x; fp.use_tab = (l == 0) ? 1 : 0;
      int bs = 0;
      for (int m = 3; m < 5; m++) {
        int i = m - 3;
        fp.gidx[i] = rowm[m]; fp.xp[i] = xp[m];
        fp.vals[i] = vals[m]; fp.tab[i] = Tabs + 1152 + (size_t)i * 256;
        fp.Wa[i] = Wpk + (size_t)(16 + l * 2 + i) * 4096;
        fp.ba[i] = cb_a2p + (l * 2 + i) * 64;
        fp.Bp[i] = Bp + (size_t)(6 + l * 2 + i) * 12288;
        fp.Kb[i] = cKb + (l * 2 + i) * 64;
        fp.k[i] = Km[m]; fp.P[i] = Em[m] / Km[m]; fp.ppb[i] = Ppb[m];
        fp.blk_start[i] = bs;
        bs += (fp.P[i] + fp.ppb[i] - 1) / fp.ppb[i];
      }
      k_fused<<<bs, 256, 0, stream>>>(fp);

      Apply2Params ap{};
      ap.nm = 2; ap.bucket = bucket;
      for (int m = 3; m < 5; m++) {
        int i = m - 3;
        ap.xp[i] = (const f16*)xp[m];
        ap.cnt[i] = cnt + (size_t)m * 100000;
        ap.basea[i] = basea + (size_t)m * 100000;
        ap.Wp[i] = p2aW(l, m); ap.bias[i] = p2aB(l, m);
      }
      k_apply2<<<apply_blocks, 256, 0, stream>>>(ap, x);
    }
  }

  // ---- head (basea entries for the batch segment are GLOBAL bucket positions)
  k_meanscatter<<<NBATCH / 4, 256, 0, stream>>>(x, bucket, basea + 500000,
                                                cnt + 500000, g1, NBATCH);
  k_head<<<NBATCH / 32, 256, 0, stream>>>(g1, alW, alb, g2);
  k_final<<<NBATCH / 4, 256, 0, stream>>>(g2, linW, linb, (float*)d_out);
}